// Round 2
// baseline (548.652 us; speedup 1.0000x reference)
//
#include <hip/hip_runtime.h>
#include <hip/hip_bf16.h>
#include <cstdint>

typedef __hip_bfloat16 bf16;
using short8 = __attribute__((ext_vector_type(8))) short;
using f32x4  = __attribute__((ext_vector_type(4))) float;

#define DEV __device__ __forceinline__

static constexpr int Bb = 8;
static constexpr int S  = 2048;
static constexpr int D  = 1024;
static constexpr long ROWS = (long)Bb * S;   // 16384

DEV void async_copy16(const void* g, void* l) {
    __builtin_amdgcn_global_load_lds((const __attribute__((address_space(1))) void*)g,
                                     (__attribute__((address_space(3))) void*)l,
                                     16, 0, 0);
}

DEV float wsum(float v) {
#pragma unroll
    for (int off = 32; off > 0; off >>= 1) v += __shfl_xor(v, off, 64);
    return v;
}

DEV float bf2f(bf16 x) { return __bfloat162float(x); }
DEV bf16  f2bf(float x) { return __float2bfloat16(x); }

// -------- weight transpose + cast: W fp32 (K x N) -> WT bf16 (N x Kp), zero-pad k >= K --------
__global__ void transpose_pad(const float* __restrict__ W, bf16* __restrict__ WT,
                              int K, int N, int Kp) {
    long idx = (long)blockIdx.x * 256 + threadIdx.x;
    if (idx >= (long)N * Kp) return;
    int n = (int)(idx / Kp), k = (int)(idx % Kp);
    WT[idx] = (k < K) ? f2bf(W[(long)k * N + n]) : f2bf(0.0f);
}

// -------- scan phase A: per-chunk partial sums (fp32 in) --------
// grid: (D/256, 16, B)  chunk len 128
__global__ void scan_partial(const float* __restrict__ x, float* __restrict__ part) {
    int d = blockIdx.x * 256 + threadIdx.x;
    int c = blockIdx.y, b = blockIdx.z;
    const float* p = x + ((long)b * S + (long)c * 128) * D + d;
    float s = 0.f;
#pragma unroll 8
    for (int j = 0; j < 128; ++j) s += p[(long)j * D];
    part[((long)(b * 16 + c)) * D + d] = s;
}

// -------- scan phase B: exclusive scan over 16 chunks + total --------
__global__ void scan_offsets(float* __restrict__ part, float* __restrict__ total) {
    int idx = blockIdx.x * 256 + threadIdx.x;   // 8192
    int b = idx >> 10, d = idx & 1023;
    float* p = part + (long)(b * 16) * D + d;
    float run = 0.f;
#pragma unroll
    for (int c = 0; c < 16; ++c) { float v = p[(long)c * D]; p[(long)c * D] = run; run += v; }
    total[idx] = run;
}

// -------- scan phase C: emit ctx (bf16), xb (bf16 cast of x), and exact fp32 x passthrough --------
__global__ void scan_ctx(const float* __restrict__ x, const float* __restrict__ part,
                         const float* __restrict__ total, bf16* __restrict__ ctxb,
                         bf16* __restrict__ xb, float* __restrict__ outx) {
    int d = blockIdx.x * 256 + threadIdx.x;
    int c = blockIdx.y, b = blockIdx.z;
    float run = part[((long)(b * 16 + c)) * D + d];
    float tot = total[(long)b * D + d];
    const long base = ((long)b * S + (long)c * 128) * D + d;
    const float* px = x + base;
    bf16* pc = ctxb + base;
    bf16* pb = xb + base;
    float* po = outx + base;
    for (int j = 0; j < 128; ++j) {
        int s = c * 128 + j;
        float xv = px[(long)j * D];
        float ctxv;
        if (s == 0 || s == S - 1) {
            ctxv = (tot - xv) * (1.0f / (float)(S - 1));
        } else {
            ctxv = 0.5f * (run / (float)s + (tot - run - xv) / (float)(S - 1 - s));
        }
        pc[(long)j * D] = f2bf(ctxv);
        pb[(long)j * D] = f2bf(xv);
        po[(long)j * D] = xv;           // exact fp32 copy
        run += xv;
    }
}

// -------- MFMA GEMM: O[M,N] = act(A[M,Ktot] * BT[N,Ktot]^T + bias), bf16 in, bf16 out --------
// A split in K: k < K1 from A1 (lda1), k >= K1 from A2 (lda2). 128x128 tile, BK=64.
template <bool RELU>
__global__ __launch_bounds__(256) void gemm_bt(
    const bf16* __restrict__ A1, int lda1, int K1,
    const bf16* __restrict__ A2, int lda2,
    const bf16* __restrict__ BT,
    const float* __restrict__ bias,
    bf16* __restrict__ O,
    int N, int Ktot)
{
    __shared__ __align__(16) bf16 ldsA[128 * 64];
    __shared__ __align__(16) bf16 ldsB[128 * 64];

    const int tid = threadIdx.x;
    const int w = tid >> 6, l = tid & 63;
    const int row0 = blockIdx.y * 128, col0 = blockIdx.x * 128;
    const int wm = (w >> 1) * 64, wn = (w & 1) * 64;

    f32x4 acc[4][4];
#pragma unroll
    for (int i = 0; i < 4; ++i)
#pragma unroll
        for (int j = 0; j < 4; ++j) acc[i][j] = (f32x4){0.f, 0.f, 0.f, 0.f};

    const int srow = l >> 3;        // 0..7
    const int sk = (l & 7) * 8;     // bf16 elements, 16B granules

    const int lm = l & 15, lq = l >> 4, lk = lq * 8;

    for (int k0 = 0; k0 < Ktot; k0 += 64) {
        const bf16* Abase; int lda; int kk;
        if (k0 < K1) { Abase = A1; lda = lda1; kk = k0; }
        else         { Abase = A2; lda = lda2; kk = k0 - K1; }
#pragma unroll
        for (int i = 0; i < 4; ++i) {
            int r = w * 32 + i * 8;
            const bf16* g = Abase + (long)(row0 + r + srow) * lda + kk + sk;
            async_copy16(g, &ldsA[r * 64]);
        }
#pragma unroll
        for (int i = 0; i < 4; ++i) {
            int r = w * 32 + i * 8;
            const bf16* g = BT + (long)(col0 + r + srow) * Ktot + k0 + sk;
            async_copy16(g, &ldsB[r * 64]);
        }
        __syncthreads();
#pragma unroll
        for (int kk2 = 0; kk2 < 64; kk2 += 32) {
            short8 af[4], bfr[4];
#pragma unroll
            for (int i = 0; i < 4; ++i)
                af[i] = *(const short8*)&ldsA[(wm + i * 16 + lm) * 64 + kk2 + lk];
#pragma unroll
            for (int j = 0; j < 4; ++j)
                bfr[j] = *(const short8*)&ldsB[(wn + j * 16 + lm) * 64 + kk2 + lk];
#pragma unroll
            for (int i = 0; i < 4; ++i)
#pragma unroll
                for (int j = 0; j < 4; ++j)
                    acc[i][j] = __builtin_amdgcn_mfma_f32_16x16x32_bf16(af[i], bfr[j], acc[i][j], 0, 0, 0);
        }
        __syncthreads();
    }

#pragma unroll
    for (int j = 0; j < 4; ++j) {
        int col = col0 + wn + j * 16 + lm;
        float bv = bias[col];
#pragma unroll
        for (int i = 0; i < 4; ++i) {
#pragma unroll
            for (int r = 0; r < 4; ++r) {
                int row = row0 + wm + i * 16 + lq * 4 + r;
                float v = acc[i][j][r] + bv;
                if (RELU) v = fmaxf(v, 0.f);
                O[(long)row * N + col] = f2bf(v);
            }
        }
    }
}

// -------- cc2 + softmax + relevance + tail pack (wave per row) --------
__global__ void cc2_softmax(const bf16* __restrict__ Y1, const float* __restrict__ W2,
                            const float* __restrict__ b2, float* __restrict__ ctf,
                            float* __restrict__ out_ct, bf16* __restrict__ tail,
                            float* __restrict__ out_rel) {
    int w = threadIdx.x >> 6, l = threadIdx.x & 63;
    long r = (long)blockIdx.x * 4 + w;
    const bf16* y = Y1 + r * 512 + l * 8;
    float yv[8];
#pragma unroll
    for (int j = 0; j < 8; ++j) yv[j] = bf2f(y[j]);
    float s[5] = {0, 0, 0, 0, 0};
#pragma unroll
    for (int j = 0; j < 8; ++j) {
        const float* wp = W2 + (long)(l * 8 + j) * 5;
#pragma unroll
        for (int cc = 0; cc < 5; ++cc) s[cc] += yv[j] * wp[cc];
    }
#pragma unroll
    for (int cc = 0; cc < 5; ++cc) { s[cc] = wsum(s[cc]); }
#pragma unroll
    for (int cc = 0; cc < 5; ++cc) s[cc] += b2[cc];
    float mx = s[0];
#pragma unroll
    for (int cc = 1; cc < 5; ++cc) mx = fmaxf(mx, s[cc]);
    float e[5]; float den = 0.f;
#pragma unroll
    for (int cc = 0; cc < 5; ++cc) { e[cc] = expf(s[cc] - mx); den += e[cc]; }
    float inv = 1.f / den;
    if (l < 5) {
        float p = 0.f;
#pragma unroll
        for (int cc = 0; cc < 5; ++cc) p = (l == cc) ? e[cc] * inv : p;
        ctf[r * 5 + l] = p;
        out_ct[r * 5 + l] = p;
        tail[r * 64 + l] = f2bf(p);
    } else {
        tail[r * 64 + l] = f2bf(0.f);
    }
    if (l == 0) out_rel[r] = 1.f - e[3] * inv;
}

// -------- be2: sigmoid(Y3 . W + b) * (ct . bw)  (wave per row) --------
__global__ void be2_kernel(const bf16* __restrict__ Y3, const float* __restrict__ Wv,
                           const float* __restrict__ bv, const float* __restrict__ ctf,
                           float* __restrict__ out_wb) {
    int w = threadIdx.x >> 6, l = threadIdx.x & 63;
    long r = (long)blockIdx.x * 4 + w;
    const bf16* y = Y3 + r * 256 + l * 4;
    const float* wp = Wv + l * 4;
    float s = 0.f;
#pragma unroll
    for (int j = 0; j < 4; ++j) s += bf2f(y[j]) * wp[j];
    s = wsum(s);
    if (l == 0) {
        float sig = 1.f / (1.f + expf(-(s + bv[0])));
        const float bw[5] = {0.1f, 1.0f, 0.8f, 0.3f, 0.5f};
        float cb = 0.f;
#pragma unroll
        for (int cc = 0; cc < 5; ++cc) cb += ctf[r * 5 + cc] * bw[cc];
        out_wb[r] = sig * cb;
    }
}

// -------- cr2: sigmoid(Y4 . W + b)  (wave per row, len 512) --------
__global__ void cr2_kernel(const bf16* __restrict__ Y4, const float* __restrict__ Wv,
                           const float* __restrict__ bv, float* __restrict__ out_cred) {
    int w = threadIdx.x >> 6, l = threadIdx.x & 63;
    long r = (long)blockIdx.x * 4 + w;
    const bf16* y = Y4 + r * 512 + l * 8;
    const float* wp = Wv + l * 8;
    float s = 0.f;
#pragma unroll
    for (int j = 0; j < 8; ++j) s += bf2f(y[j]) * wp[j];
    s = wsum(s);
    if (l == 0) out_cred[r] = 1.f / (1.f + expf(-(s + bv[0])));
}

// -------- LN + gelu + cd2 dot + sigmoid + enhanced (wave per row) --------
__global__ void ln_gelu_cd2(const bf16* __restrict__ H, const float* __restrict__ g,
                            const float* __restrict__ be, const float* __restrict__ Wd,
                            const float* __restrict__ bd, const float* __restrict__ ctf,
                            float* __restrict__ out_enh) {
    int w = threadIdx.x >> 6, l = threadIdx.x & 63;
    long r = (long)blockIdx.x * 4 + w;
    const bf16* h = H + r * 1024 + l * 16;
    float v[16];
    float sum = 0.f, sum2 = 0.f;
#pragma unroll
    for (int j = 0; j < 16; ++j) { v[j] = bf2f(h[j]); sum += v[j]; }
#pragma unroll
    for (int j = 0; j < 16; ++j) sum2 += v[j] * v[j];
    sum = wsum(sum);
    sum2 = wsum(sum2);
    float mu = sum * (1.f / 1024.f);
    float var = sum2 * (1.f / 1024.f) - mu * mu;
    float rstd = rsqrtf(var + 1e-5f);
    float dot = 0.f;
#pragma unroll
    for (int j = 0; j < 16; ++j) {
        int dc = l * 16 + j;
        float hn = (v[j] - mu) * rstd * g[dc] + be[dc];
        float ge = 0.5f * hn * (1.f + erff(hn * 0.70710678118654752f));
        dot += ge * Wd[dc];
    }
    dot = wsum(dot);
    if (l == 0) {
        float contr = 1.f / (1.f + expf(-(dot + bd[0])));
        out_enh[r] = fmaxf(contr, ctf[r * 5 + 2]);
    }
}

extern "C" void kernel_launch(void* const* d_in, const int* in_sizes, int n_in,
                              void* d_out, int out_size, void* d_ws, size_t ws_size,
                              hipStream_t stream) {
    const float* x      = (const float*)d_in[0];
    const float* W_cc1  = (const float*)d_in[1];
    const float* b_cc1  = (const float*)d_in[2];
    const float* W_cc2  = (const float*)d_in[3];
    const float* b_cc2  = (const float*)d_in[4];
    const float* W_cd1  = (const float*)d_in[5];
    const float* b_cd1  = (const float*)d_in[6];
    const float* g_ln   = (const float*)d_in[7];
    const float* be_ln  = (const float*)d_in[8];
    const float* W_cd2  = (const float*)d_in[9];
    const float* b_cd2  = (const float*)d_in[10];
    const float* W_be1  = (const float*)d_in[11];
    const float* b_be1  = (const float*)d_in[12];
    const float* W_be2  = (const float*)d_in[13];
    const float* b_be2  = (const float*)d_in[14];
    const float* W_cr1  = (const float*)d_in[15];
    const float* b_cr1  = (const float*)d_in[16];
    const float* W_cr2  = (const float*)d_in[17];
    const float* b_cr2  = (const float*)d_in[18];

    float* out = (float*)d_out;
    float* out_x    = out;
    float* out_ct   = out_x + (long)ROWS * D;    // 16777216
    float* out_enh  = out_ct + ROWS * 5;         // +81920
    float* out_wb   = out_enh + ROWS;
    float* out_rel  = out_wb + ROWS;
    float* out_cred = out_rel + ROWS;

    char* cur = (char*)d_ws;
    auto alloc = [&](size_t bytes) { char* p = cur; cur += (bytes + 255) & ~(size_t)255; return p; };

    bf16* wcc1T = (bf16*)alloc((size_t)512 * 1024 * 2);
    bf16* wcd1T = (bf16*)alloc((size_t)1024 * 2048 * 2);
    bf16* wbe1T = (bf16*)alloc((size_t)256 * 1024 * 2);
    bf16* wcr1T = (bf16*)alloc((size_t)512 * 1088 * 2);
    bf16* xb    = (bf16*)alloc((size_t)ROWS * 1024 * 2);  // bf16 cast of x
    bf16* ctxb  = (bf16*)alloc((size_t)ROWS * 1024 * 2);  // ctx bf16; later reused for Y4
    bf16* regB  = (bf16*)alloc((size_t)ROWS * 1024 * 2);  // Y1 -> Y3 -> Hraw (phase-aliased)
    bf16* tail  = (bf16*)alloc((size_t)ROWS * 64 * 2);
    float* ctf  = (float*)alloc((size_t)ROWS * 5 * 4);
    float* part = (float*)alloc((size_t)Bb * 16 * 1024 * 4);
    float* totl = (float*)alloc((size_t)Bb * 1024 * 4);

    bf16* Y1   = regB;                  // 16384 x 512
    bf16* Y3   = regB;                  // 16384 x 256 (after cc2 consumed Y1)
    bf16* Hraw = regB;                  // 16384 x 1024 (after be2 consumed Y3)
    bf16* Y4   = ctxb;                  // 16384 x 512 (after G2 consumed ctxb)

    // weight transposes (fp32 -> bf16, B^T layout)
    transpose_pad<<<(512 * 1024 + 255) / 256, 256, 0, stream>>>(W_cc1, wcc1T, 1024, 512, 1024);
    transpose_pad<<<(1024 * 2048 + 255) / 256, 256, 0, stream>>>(W_cd1, wcd1T, 2048, 1024, 2048);
    transpose_pad<<<(256 * 1024 + 255) / 256, 256, 0, stream>>>(W_be1, wbe1T, 1024, 256, 1024);
    transpose_pad<<<(512 * 1088 + 255) / 256, 256, 0, stream>>>(W_cr1, wcr1T, 1029, 512, 1088);

    // ctx scan (also emits xb bf16 and exact fp32 x passthrough)
    scan_partial<<<dim3(4, 16, 8), 256, 0, stream>>>(x, part);
    scan_offsets<<<32, 256, 0, stream>>>(part, totl);
    scan_ctx<<<dim3(4, 16, 8), 256, 0, stream>>>(x, part, totl, ctxb, xb, out_x);

    // G1: cc1 relu -> Y1 ; cc2 + softmax -> ctf, out_ct, tail, out_rel
    gemm_bt<true><<<dim3(512 / 128, ROWS / 128), 256, 0, stream>>>(
        xb, 1024, 1024, xb, 1024, wcc1T, b_cc1, Y1, 512, 1024);
    cc2_softmax<<<ROWS / 4, 256, 0, stream>>>(Y1, W_cc2, b_cc2, ctf, out_ct, tail, out_rel);

    // G3: be1 relu -> Y3 ; be2 -> out_wb
    gemm_bt<true><<<dim3(256 / 128, ROWS / 128), 256, 0, stream>>>(
        xb, 1024, 1024, xb, 1024, wbe1T, b_be1, Y3, 256, 1024);
    be2_kernel<<<ROWS / 4, 256, 0, stream>>>(Y3, W_be2, b_be2, ctf, out_wb);

    // G2: cd1 over [x | ctx] -> Hraw ; LN+gelu+cd2 -> out_enh
    gemm_bt<false><<<dim3(1024 / 128, ROWS / 128), 256, 0, stream>>>(
        xb, 1024, 1024, ctxb, 1024, wcd1T, b_cd1, Hraw, 1024, 2048);
    ln_gelu_cd2<<<ROWS / 4, 256, 0, stream>>>(Hraw, g_ln, be_ln, W_cd2, b_cd2, ctf, out_enh);

    // G4: cr1 over [x | tail] -> Y4 ; cr2 -> out_cred
    gemm_bt<true><<<dim3(512 / 128, ROWS / 128), 256, 0, stream>>>(
        xb, 1024, 1024, tail, 64, wcr1T, b_cr1, Y4, 512, 1088);
    cr2_kernel<<<ROWS / 4, 256, 0, stream>>>(Y4, W_cr2, b_cr2, out_cred);

    (void)in_sizes; (void)n_in; (void)out_size; (void)ws_size;
}

// Round 3
// 506.803 us; speedup vs baseline: 1.0826x; 1.0826x over previous
//
#include <hip/hip_runtime.h>
#include <hip/hip_bf16.h>
#include <cstdint>

typedef __hip_bfloat16 bf16;
using short8 = __attribute__((ext_vector_type(8))) short;
using f32x4  = __attribute__((ext_vector_type(4))) float;

#define DEV __device__ __forceinline__

static constexpr int Bb = 8;
static constexpr int S  = 2048;
static constexpr int D  = 1024;
static constexpr long ROWS = (long)Bb * S;   // 16384
static constexpr int NBIG = 2304;            // 512(cc1) + 256(be1) + 512(cr1-x) + 1024(cd1-top)

DEV void async_copy16(const void* g, void* l) {
    __builtin_amdgcn_global_load_lds((const __attribute__((address_space(1))) void*)g,
                                     (__attribute__((address_space(3))) void*)l,
                                     16, 0, 0);
}

DEV float wsum(float v) {
#pragma unroll
    for (int off = 32; off > 0; off >>= 1) v += __shfl_xor(v, off, 64);
    return v;
}

DEV float bf2f(bf16 x) { return __bfloat162float(x); }
DEV bf16  f2bf(float x) { return __float2bfloat16(x); }

// -------- transpose+cast a column slice: W fp32 [.., ldw], rows row0..row0+1023,
// cols col0..col0+ncols -> WT bf16 at dstOff, layout [ncols][1024] k-contiguous --------
__global__ void transpose_cast(const float* __restrict__ W, int ldw, int row0, int col0,
                               bf16* __restrict__ WT, int ncols, long dstOff) {
    long idx = (long)blockIdx.x * 256 + threadIdx.x;
    if (idx >= (long)ncols * 1024) return;
    int n = (int)(idx >> 10), k = (int)(idx & 1023);
    WT[dstOff + idx] = f2bf(W[(long)(row0 + k) * ldw + col0 + n]);
}

// -------- concat biases into biasAll[2304] --------
__global__ void build_bias(const float* __restrict__ b1, const float* __restrict__ b2,
                           const float* __restrict__ b3, const float* __restrict__ b4,
                           float* __restrict__ o) {
    int i = blockIdx.x * 256 + threadIdx.x;
    if (i >= NBIG) return;
    float v;
    if (i < 512)       v = b1[i];
    else if (i < 768)  v = b2[i - 512];
    else if (i < 1280) v = b3[i - 768];
    else               v = b4[i - 1280];
    o[i] = v;
}

// -------- scan phase A: per-chunk partial sums --------
__global__ void scan_partial(const float* __restrict__ x, float* __restrict__ part) {
    int d = blockIdx.x * 256 + threadIdx.x;
    int c = blockIdx.y, b = blockIdx.z;
    const float* p = x + ((long)b * S + (long)c * 128) * D + d;
    float s = 0.f;
#pragma unroll 8
    for (int j = 0; j < 128; ++j) s += p[(long)j * D];
    part[((long)(b * 16 + c)) * D + d] = s;
}

// -------- scan phase B: exclusive scan over 16 chunks + total --------
__global__ void scan_offsets(float* __restrict__ part, float* __restrict__ total) {
    int idx = blockIdx.x * 256 + threadIdx.x;   // 8192
    int b = idx >> 10, d = idx & 1023;
    float* p = part + (long)(b * 16) * D + d;
    float run = 0.f;
#pragma unroll
    for (int c = 0; c < 16; ++c) { float v = p[(long)c * D]; p[(long)c * D] = run; run += v; }
    total[idx] = run;
}

// -------- scan phase C: emit ctx (bf16), xb (bf16), exact fp32 x passthrough --------
__global__ void scan_ctx(const float* __restrict__ x, const float* __restrict__ part,
                         const float* __restrict__ total, bf16* __restrict__ ctxb,
                         bf16* __restrict__ xb, float* __restrict__ outx) {
    int d = blockIdx.x * 256 + threadIdx.x;
    int c = blockIdx.y, b = blockIdx.z;
    float run = part[((long)(b * 16 + c)) * D + d];
    float tot = total[(long)b * D + d];
    const long base = ((long)b * S + (long)c * 128) * D + d;
    const float* px = x + base;
    bf16* pc = ctxb + base;
    bf16* pb = xb + base;
    float* po = outx + base;
    for (int j = 0; j < 128; ++j) {
        int s = c * 128 + j;
        float xv = px[(long)j * D];
        float ctxv;
        if (s == 0 || s == S - 1) {
            ctxv = (tot - xv) * (1.0f / (float)(S - 1));
        } else {
            ctxv = 0.5f * (run / (float)s + (tot - run - xv) / (float)(S - 1 - s));
        }
        pc[(long)j * D] = f2bf(ctxv);
        pb[(long)j * D] = f2bf(xv);
        po[(long)j * D] = xv;           // exact fp32 copy
        run += xv;
    }
}

// -------- MFMA GEMM, XOR-swizzled LDS: O[M,N] = A[M,K]*BT[N,K]^T (+bias) (+relu cols<reluN)
// LDS tile [128 rows][8 kblocks of 16B]; kblock g for row r stored at slot g^(r&7).
// Swizzle applied via the global source address (LDS dst of global_load_lds is
// wave-uniform base + lane*16 and stays contiguous); inverted on ds_read side.
__global__ __launch_bounds__(256) void gemm_bt(
    const bf16* __restrict__ A, const bf16* __restrict__ BT,
    const float* __restrict__ bias, bf16* __restrict__ O,
    int N, int K, int reluN, int useBias)
{
    __shared__ __align__(16) bf16 ldsA[128 * 64];
    __shared__ __align__(16) bf16 ldsB[128 * 64];

    const int tid = threadIdx.x;
    const int w = tid >> 6, l = tid & 63;
    const int row0 = blockIdx.y * 128, col0 = blockIdx.x * 128;
    const int wm = (w >> 1) * 64, wn = (w & 1) * 64;

    f32x4 acc[4][4];
#pragma unroll
    for (int i = 0; i < 4; ++i)
#pragma unroll
        for (int j = 0; j < 4; ++j) acc[i][j] = (f32x4){0.f, 0.f, 0.f, 0.f};

    // staging: lane l covers LDS row (8i+w*32)+(l>>3), kblock slot (l&7)
    const int lr = l >> 3;                       // row within 8-row group
    const int cb = l & 7;                        // destination kblock slot
    const int ksrc = ((cb ^ lr) << 3);           // swizzled source k offset (elements)

    // fragment read: lane lm=l&15, quad lq=l>>4
    const int lm = l & 15, lq = l >> 4;
    const int rsw = lm & 7;                      // row&7 for swizzle inversion

    for (int k0 = 0; k0 < K; k0 += 64) {
#pragma unroll
        for (int i = 0; i < 4; ++i) {
            int r = w * 32 + i * 8;
            async_copy16(A + (long)(row0 + r + lr) * K + k0 + ksrc, &ldsA[r * 64]);
            async_copy16(BT + (long)(col0 + r + lr) * K + k0 + ksrc, &ldsB[r * 64]);
        }
        __syncthreads();
#pragma unroll
        for (int h = 0; h < 2; ++h) {
            const int slot = ((h * 4 + lq) ^ rsw) << 3;   // element offset of 16B chunk
            short8 af[4], bfr[4];
#pragma unroll
            for (int i = 0; i < 4; ++i)
                af[i] = *(const short8*)&ldsA[(wm + i * 16 + lm) * 64 + slot];
#pragma unroll
            for (int j = 0; j < 4; ++j)
                bfr[j] = *(const short8*)&ldsB[(wn + j * 16 + lm) * 64 + slot];
#pragma unroll
            for (int i = 0; i < 4; ++i)
#pragma unroll
                for (int j = 0; j < 4; ++j)
                    acc[i][j] = __builtin_amdgcn_mfma_f32_16x16x32_bf16(af[i], bfr[j], acc[i][j], 0, 0, 0);
        }
        __syncthreads();
    }

#pragma unroll
    for (int j = 0; j < 4; ++j) {
        int col = col0 + wn + j * 16 + lm;
        float bv = useBias ? bias[col] : 0.f;
#pragma unroll
        for (int i = 0; i < 4; ++i) {
#pragma unroll
            for (int r = 0; r < 4; ++r) {
                int row = row0 + wm + i * 16 + lq * 4 + r;
                float v = acc[i][j][r] + bv;
                if (col < reluN) v = fmaxf(v, 0.f);
                O[(long)row * N + col] = f2bf(v);
            }
        }
    }
}

// -------- cc2 + softmax + relevance (wave per row); Y1 = YB cols [0,512) --------
__global__ void cc2_softmax(const bf16* __restrict__ YB, const float* __restrict__ W2,
                            const float* __restrict__ b2, float* __restrict__ ctf,
                            float* __restrict__ out_ct, float* __restrict__ out_rel) {
    int w = threadIdx.x >> 6, l = threadIdx.x & 63;
    long r = (long)blockIdx.x * 4 + w;
    const bf16* y = YB + r * NBIG + l * 8;
    float yv[8];
#pragma unroll
    for (int j = 0; j < 8; ++j) yv[j] = bf2f(y[j]);
    float s[5] = {0, 0, 0, 0, 0};
#pragma unroll
    for (int j = 0; j < 8; ++j) {
        const float* wp = W2 + (long)(l * 8 + j) * 5;
#pragma unroll
        for (int cc = 0; cc < 5; ++cc) s[cc] += yv[j] * wp[cc];
    }
#pragma unroll
    for (int cc = 0; cc < 5; ++cc) { s[cc] = wsum(s[cc]); }
#pragma unroll
    for (int cc = 0; cc < 5; ++cc) s[cc] += b2[cc];
    float mx = s[0];
#pragma unroll
    for (int cc = 1; cc < 5; ++cc) mx = fmaxf(mx, s[cc]);
    float e[5]; float den = 0.f;
#pragma unroll
    for (int cc = 0; cc < 5; ++cc) { e[cc] = expf(s[cc] - mx); den += e[cc]; }
    float inv = 1.f / den;
    if (l < 5) {
        float p = 0.f;
#pragma unroll
        for (int cc = 0; cc < 5; ++cc) p = (l == cc) ? e[cc] * inv : p;
        ctf[r * 5 + l] = p;
        out_ct[r * 5 + l] = p;
    }
    if (l == 0) out_rel[r] = 1.f - e[3] * inv;
}

// -------- be2: sigmoid(relu'd Y3 . W + b) * (ct . bw); Y3 = YB cols [512,768) --------
__global__ void be2_kernel(const bf16* __restrict__ YB, const float* __restrict__ Wv,
                           const float* __restrict__ bv, const float* __restrict__ ctf,
                           float* __restrict__ out_wb) {
    int w = threadIdx.x >> 6, l = threadIdx.x & 63;
    long r = (long)blockIdx.x * 4 + w;
    const bf16* y = YB + r * NBIG + 512 + l * 4;
    const float* wp = Wv + l * 4;
    float s = 0.f;
#pragma unroll
    for (int j = 0; j < 4; ++j) s += bf2f(y[j]) * wp[j];
    s = wsum(s);
    if (l == 0) {
        float sig = 1.f / (1.f + expf(-(s + bv[0])));
        const float bw[5] = {0.1f, 1.0f, 0.8f, 0.3f, 0.5f};
        float cb = 0.f;
#pragma unroll
        for (int cc = 0; cc < 5; ++cc) cb += ctf[r * 5 + cc] * bw[cc];
        out_wb[r] = sig * cb;
    }
}

// -------- cr2: rank-5 ct-correction + relu + dot + sigmoid; Y4lin = YB cols [768,1280) --------
__global__ void cr2_kernel(const bf16* __restrict__ YB, const float* __restrict__ W5,
                           const float* __restrict__ Wv, const float* __restrict__ bv,
                           const float* __restrict__ ctf, float* __restrict__ out_cred) {
    int w = threadIdx.x >> 6, l = threadIdx.x & 63;
    long r = (long)blockIdx.x * 4 + w;
    const bf16* y = YB + r * NBIG + 768 + l * 8;
    float ct[5];
#pragma unroll
    for (int cc = 0; cc < 5; ++cc) ct[cc] = ctf[r * 5 + cc];
    float s = 0.f;
#pragma unroll
    for (int j = 0; j < 8; ++j) {
        int col = l * 8 + j;
        float corr = 0.f;
#pragma unroll
        for (int cc = 0; cc < 5; ++cc) corr += ct[cc] * W5[(long)cc * 512 + col];
        float v = fmaxf(bf2f(y[j]) + corr, 0.f);
        s += v * Wv[col];
    }
    s = wsum(s);
    if (l == 0) out_cred[r] = 1.f / (1.f + expf(-(s + bv[0])));
}

// -------- LN + gelu + cd2 dot + sigmoid + enhanced; H = YB cols [1280,2304) + H2 --------
__global__ void ln_gelu_cd2(const bf16* __restrict__ YB, const bf16* __restrict__ H2,
                            const float* __restrict__ g, const float* __restrict__ be,
                            const float* __restrict__ Wd, const float* __restrict__ bd,
                            const float* __restrict__ ctf, float* __restrict__ out_enh) {
    int w = threadIdx.x >> 6, l = threadIdx.x & 63;
    long r = (long)blockIdx.x * 4 + w;
    const bf16* h1 = YB + r * NBIG + 1280 + l * 16;
    const bf16* h2 = H2 + r * 1024 + l * 16;
    float v[16];
    float sum = 0.f, sum2 = 0.f;
#pragma unroll
    for (int j = 0; j < 16; ++j) { v[j] = bf2f(h1[j]) + bf2f(h2[j]); sum += v[j]; }
#pragma unroll
    for (int j = 0; j < 16; ++j) sum2 += v[j] * v[j];
    sum = wsum(sum);
    sum2 = wsum(sum2);
    float mu = sum * (1.f / 1024.f);
    float var = sum2 * (1.f / 1024.f) - mu * mu;
    float rstd = rsqrtf(var + 1e-5f);
    float dot = 0.f;
#pragma unroll
    for (int j = 0; j < 16; ++j) {
        int dc = l * 16 + j;
        float hn = (v[j] - mu) * rstd * g[dc] + be[dc];
        float ge = 0.5f * hn * (1.f + erff(hn * 0.70710678118654752f));
        dot += ge * Wd[dc];
    }
    dot = wsum(dot);
    if (l == 0) {
        float contr = 1.f / (1.f + expf(-(dot + bd[0])));
        out_enh[r] = fmaxf(contr, ctf[r * 5 + 2]);
    }
}

extern "C" void kernel_launch(void* const* d_in, const int* in_sizes, int n_in,
                              void* d_out, int out_size, void* d_ws, size_t ws_size,
                              hipStream_t stream) {
    const float* x      = (const float*)d_in[0];
    const float* W_cc1  = (const float*)d_in[1];
    const float* b_cc1  = (const float*)d_in[2];
    const float* W_cc2  = (const float*)d_in[3];
    const float* b_cc2  = (const float*)d_in[4];
    const float* W_cd1  = (const float*)d_in[5];
    const float* b_cd1  = (const float*)d_in[6];
    const float* g_ln   = (const float*)d_in[7];
    const float* be_ln  = (const float*)d_in[8];
    const float* W_cd2  = (const float*)d_in[9];
    const float* b_cd2  = (const float*)d_in[10];
    const float* W_be1  = (const float*)d_in[11];
    const float* b_be1  = (const float*)d_in[12];
    const float* W_be2  = (const float*)d_in[13];
    const float* b_be2  = (const float*)d_in[14];
    const float* W_cr1  = (const float*)d_in[15];
    const float* b_cr1  = (const float*)d_in[16];
    const float* W_cr2  = (const float*)d_in[17];
    const float* b_cr2  = (const float*)d_in[18];

    float* out = (float*)d_out;
    float* out_x    = out;
    float* out_ct   = out_x + (long)ROWS * D;
    float* out_enh  = out_ct + ROWS * 5;
    float* out_wb   = out_enh + ROWS;
    float* out_rel  = out_wb + ROWS;
    float* out_cred = out_rel + ROWS;

    char* cur = (char*)d_ws;
    auto alloc = [&](size_t bytes) { char* p = cur; cur += (bytes + 255) & ~(size_t)255; return p; };

    bf16* WT     = (bf16*)alloc((size_t)NBIG * 1024 * 2);   // fused B^T [2304][1024]
    bf16* WTb    = (bf16*)alloc((size_t)1024 * 1024 * 2);   // cd1 bottom B^T [1024][1024]
    float* biasA = (float*)alloc((size_t)NBIG * 4);
    bf16* xb     = (bf16*)alloc((size_t)ROWS * 1024 * 2);
    bf16* ctxb   = (bf16*)alloc((size_t)ROWS * 1024 * 2);
    bf16* YB     = (bf16*)alloc((size_t)ROWS * NBIG * 2);   // fused GEMM output
    bf16* H2     = (bf16*)alloc((size_t)ROWS * 1024 * 2);   // ctx @ cd1-bottom
    float* ctf   = (float*)alloc((size_t)ROWS * 5 * 4);
    float* part  = (float*)alloc((size_t)Bb * 16 * 1024 * 4);
    float* totl  = (float*)alloc((size_t)Bb * 1024 * 4);

    // weight prep: fused B^T = [W_cc1 | W_be1 | W_cr1[:1024] | W_cd1[:1024]]^T, bf16
    transpose_cast<<<2048, 256, 0, stream>>>(W_cc1, 512, 0, 0, WT, 512, 0);
    transpose_cast<<<1024, 256, 0, stream>>>(W_be1, 256, 0, 0, WT, 256, (long)512 * 1024);
    transpose_cast<<<2048, 256, 0, stream>>>(W_cr1, 512, 0, 0, WT, 512, (long)768 * 1024);
    transpose_cast<<<4096, 256, 0, stream>>>(W_cd1, 1024, 0, 0, WT, 1024, (long)1280 * 1024);
    transpose_cast<<<4096, 256, 0, stream>>>(W_cd1, 1024, 1024, 0, WTb, 1024, 0);
    build_bias<<<(NBIG + 255) / 256, 256, 0, stream>>>(b_cc1, b_be1, b_cr1, b_cd1, biasA);

    // ctx scan (emits xb bf16 + ctx bf16 + exact fp32 x passthrough)
    scan_partial<<<dim3(4, 16, 8), 256, 0, stream>>>(x, part);
    scan_offsets<<<32, 256, 0, stream>>>(part, totl);
    scan_ctx<<<dim3(4, 16, 8), 256, 0, stream>>>(x, part, totl, ctxb, xb, out_x);

    // fused big GEMM: YB[16384][2304] = xb @ WT^T + biasA (relu on cols < 768)
    gemm_bt<<<dim3(NBIG / 128, ROWS / 128), 256, 0, stream>>>(
        xb, WT, biasA, YB, NBIG, 1024, 768, 1);
    // ctx GEMM: H2[16384][1024] = ctxb @ WTb^T (no bias, no relu)
    gemm_bt<<<dim3(1024 / 128, ROWS / 128), 256, 0, stream>>>(
        ctxb, WTb, biasA, H2, 1024, 1024, 0, 0);

    // epilogues
    cc2_softmax<<<ROWS / 4, 256, 0, stream>>>(YB, W_cc2, b_cc2, ctf, out_ct, out_rel);
    be2_kernel<<<ROWS / 4, 256, 0, stream>>>(YB, W_be2, b_be2, ctf, out_wb);
    cr2_kernel<<<ROWS / 4, 256, 0, stream>>>(YB, W_cr1 + (long)1024 * 512, W_cr2, b_cr2, ctf, out_cred);
    ln_gelu_cd2<<<ROWS / 4, 256, 0, stream>>>(YB, H2, g_ln, be_ln, W_cd2, b_cd2, ctf, out_enh);

    (void)in_sizes; (void)n_in; (void)out_size; (void)ws_size;
}

// Round 4
// 421.633 us; speedup vs baseline: 1.3013x; 1.2020x over previous
//
#include <hip/hip_runtime.h>
#include <hip/hip_bf16.h>
#include <cstdint>

typedef __hip_bfloat16 bf16;
using short8 = __attribute__((ext_vector_type(8))) short;
using short4v = __attribute__((ext_vector_type(4))) short;
using f32x4  = __attribute__((ext_vector_type(4))) float;
using f4     = __attribute__((ext_vector_type(4))) float;

#define DEV __device__ __forceinline__

static constexpr int Bb = 8;
static constexpr int S  = 2048;
static constexpr int D  = 1024;
static constexpr long ROWS = (long)Bb * S;   // 16384
static constexpr int N1 = 1280;              // 512(cc1) + 256(be1) + 512(cr1-x)

DEV void async_copy16(const void* g, void* l) {
    __builtin_amdgcn_global_load_lds((const __attribute__((address_space(1))) void*)g,
                                     (__attribute__((address_space(3))) void*)l,
                                     16, 0, 0);
}

DEV float wsum(float v) {
#pragma unroll
    for (int off = 32; off > 0; off >>= 1) v += __shfl_xor(v, off, 64);
    return v;
}

DEV float bf2f(bf16 x) { return __bfloat162float(x); }
DEV bf16  f2bf(float x) { return __float2bfloat16(x); }
DEV float bits2f(short s) {
    unsigned u = ((unsigned)(unsigned short)s) << 16;
    float f; __builtin_memcpy(&f, &u, 4); return f;
}

// -------- LDS-tiled transpose+cast: dst[n][k] = W[row0+k][col0+n], 64x64 tiles --------
// grid: (ncols/64, nrows/64); coalesced read + coalesced write, conflict-free LDS.
__global__ __launch_bounds__(256) void transpose_tiled(
    const float* __restrict__ W, int ldw, int row0, int col0,
    bf16* __restrict__ dst, long dstLd, long dstOff)
{
    __shared__ float tile[64][65];
    const int t = threadIdx.x, tx = t & 63, ty = t >> 6;
    const int kt = blockIdx.y * 64, nt = blockIdx.x * 64;
#pragma unroll
    for (int p = 0; p < 16; ++p) {
        int k = ty * 16 + p;
        tile[k][tx] = W[(long)(row0 + kt + k) * ldw + col0 + nt + tx];
    }
    __syncthreads();
#pragma unroll
    for (int p = 0; p < 16; ++p) {
        int n = ty * 16 + p;
        dst[dstOff + (long)(nt + n) * dstLd + kt + tx] = f2bf(tile[tx][n]);
    }
}

// -------- W_cc2 (512x5) -> W2T (5x512) fp32, tiny --------
__global__ void prep_w2t(const float* __restrict__ W2, float* __restrict__ W2T) {
    int i = blockIdx.x * 256 + threadIdx.x;
    if (i >= 2560) return;
    int cc = i >> 9, n = i & 511;
    W2T[i] = W2[(long)n * 5 + cc];
}

// -------- concat biases into biasAll[1280] --------
__global__ void build_bias(const float* __restrict__ b1, const float* __restrict__ b2,
                           const float* __restrict__ b3, float* __restrict__ o) {
    int i = blockIdx.x * 256 + threadIdx.x;
    if (i >= N1) return;
    float v;
    if (i < 512)       v = b1[i];
    else if (i < 768)  v = b2[i - 512];
    else               v = b3[i - 768];
    o[i] = v;
}

// -------- scan phase A: per-chunk partial sums --------
__global__ void scan_partial(const float* __restrict__ x, float* __restrict__ part) {
    int d = blockIdx.x * 256 + threadIdx.x;
    int c = blockIdx.y, b = blockIdx.z;
    const float* p = x + ((long)b * S + (long)c * 128) * D + d;
    float s = 0.f;
#pragma unroll 8
    for (int j = 0; j < 128; ++j) s += p[(long)j * D];
    part[((long)(b * 16 + c)) * D + d] = s;
}

// -------- scan phase B: exclusive scan over 16 chunks + total --------
__global__ void scan_offsets(float* __restrict__ part, float* __restrict__ total) {
    int idx = blockIdx.x * 256 + threadIdx.x;   // 8192
    int b = idx >> 10, d = idx & 1023;
    float* p = part + (long)(b * 16) * D + d;
    float run = 0.f;
#pragma unroll
    for (int c = 0; c < 16; ++c) { float v = p[(long)c * D]; p[(long)c * D] = run; run += v; }
    total[idx] = run;
}

// -------- scan phase C: emit ctx (bf16), xb (bf16), exact fp32 x passthrough --------
__global__ void scan_ctx(const float* __restrict__ x, const float* __restrict__ part,
                         const float* __restrict__ total, bf16* __restrict__ ctxb,
                         bf16* __restrict__ xb, float* __restrict__ outx) {
    int d = blockIdx.x * 256 + threadIdx.x;
    int c = blockIdx.y, b = blockIdx.z;
    float run = part[((long)(b * 16 + c)) * D + d];
    float tot = total[(long)b * D + d];
    const long base = ((long)b * S + (long)c * 128) * D + d;
    const float* px = x + base;
    bf16* pc = ctxb + base;
    bf16* pb = xb + base;
    float* po = outx + base;
    for (int j = 0; j < 128; ++j) {
        int s = c * 128 + j;
        float xv = px[(long)j * D];
        float ctxv;
        if (s == 0 || s == S - 1) {
            ctxv = (tot - xv) * (1.0f / (float)(S - 1));
        } else {
            ctxv = 0.5f * (run / (float)s + (tot - run - xv) / (float)(S - 1 - s));
        }
        pc[(long)j * D] = f2bf(ctxv);
        pb[(long)j * D] = f2bf(xv);
        po[(long)j * D] = xv;           // exact fp32 copy
        run += xv;
    }
}

// -------- MFMA GEMM, XOR-swizzled LDS, split-A in K:
// O[M,N] = A[M,Ktot]*BT[N,Ktot]^T (+bias) (+relu on cols<reluN)
// k<K1 from A1, k>=K1 from A2 (both lda). BT row stride = Ktot.
__global__ __launch_bounds__(256) void gemm_bt(
    const bf16* __restrict__ A1, const bf16* __restrict__ A2, int K1, int lda,
    const bf16* __restrict__ BT, const float* __restrict__ bias, bf16* __restrict__ O,
    int N, int Ktot, int reluN, int useBias)
{
    __shared__ __align__(16) bf16 ldsA[128 * 64];
    __shared__ __align__(16) bf16 ldsB[128 * 64];

    const int tid = threadIdx.x;
    const int w = tid >> 6, l = tid & 63;
    const int row0 = blockIdx.y * 128, col0 = blockIdx.x * 128;
    const int wm = (w >> 1) * 64, wn = (w & 1) * 64;

    f32x4 acc[4][4];
#pragma unroll
    for (int i = 0; i < 4; ++i)
#pragma unroll
        for (int j = 0; j < 4; ++j) acc[i][j] = (f32x4){0.f, 0.f, 0.f, 0.f};

    const int lr = l >> 3;                       // row within 8-row group
    const int cb = l & 7;                        // destination kblock slot
    const int ksrc = ((cb ^ lr) << 3);           // swizzled source k offset (elements)

    const int lm = l & 15, lq = l >> 4;
    const int rsw = lm & 7;                      // row&7 for swizzle inversion

    for (int k0 = 0; k0 < Ktot; k0 += 64) {
        const bf16* Ab = (k0 < K1) ? A1 : A2;
        const int kk = (k0 < K1) ? k0 : k0 - K1;
#pragma unroll
        for (int i = 0; i < 4; ++i) {
            int r = w * 32 + i * 8;
            async_copy16(Ab + (long)(row0 + r + lr) * lda + kk + ksrc, &ldsA[r * 64]);
            async_copy16(BT + (long)(col0 + r + lr) * Ktot + k0 + ksrc, &ldsB[r * 64]);
        }
        __syncthreads();
#pragma unroll
        for (int h = 0; h < 2; ++h) {
            const int slot = ((h * 4 + lq) ^ rsw) << 3;
            short8 af[4], bfr[4];
#pragma unroll
            for (int i = 0; i < 4; ++i)
                af[i] = *(const short8*)&ldsA[(wm + i * 16 + lm) * 64 + slot];
#pragma unroll
            for (int j = 0; j < 4; ++j)
                bfr[j] = *(const short8*)&ldsB[(wn + j * 16 + lm) * 64 + slot];
#pragma unroll
            for (int i = 0; i < 4; ++i)
#pragma unroll
                for (int j = 0; j < 4; ++j)
                    acc[i][j] = __builtin_amdgcn_mfma_f32_16x16x32_bf16(af[i], bfr[j], acc[i][j], 0, 0, 0);
        }
        __syncthreads();
    }

#pragma unroll
    for (int j = 0; j < 4; ++j) {
        int col = col0 + wn + j * 16 + lm;
        float bv = useBias ? bias[col] : 0.f;
#pragma unroll
        for (int i = 0; i < 4; ++i) {
#pragma unroll
            for (int r = 0; r < 4; ++r) {
                int row = row0 + wm + i * 16 + lq * 4 + r;
                float v = acc[i][j][r] + bv;
                if (col < reluN) v = fmaxf(v, 0.f);
                O[(long)row * N + col] = f2bf(v);
            }
        }
    }
}

// -------- fused epilogue: softmax + be2 + cr2 + LN/gelu/cd2, wave per row --------
// YB[r][0:512)=relu(cc1), [512:768)=relu(be1), [768:1280)=cr1-x (raw);
// H[r][0:1024) = cd1 output (bias added, raw). All vector loads, 16B-chunk ownership.
__global__ __launch_bounds__(256) void epilogue(
    const bf16* __restrict__ YB, const bf16* __restrict__ H,
    const float* __restrict__ W2T, const float* __restrict__ b2,
    const float* __restrict__ Wbe, const float* __restrict__ bbe,
    const float* __restrict__ W5, const float* __restrict__ Wcr, const float* __restrict__ bcr,
    const float* __restrict__ g, const float* __restrict__ be,
    const float* __restrict__ Wd, const float* __restrict__ bd,
    float* __restrict__ out_ct, float* __restrict__ out_enh, float* __restrict__ out_wb,
    float* __restrict__ out_rel, float* __restrict__ out_cred)
{
    const int w = threadIdx.x >> 6, l = threadIdx.x & 63;
    const long r = (long)blockIdx.x * 4 + w;
    const bf16* yrow = YB + r * N1;

    // ---- content-type softmax (cc2) ----
    short8 y1 = *(const short8*)(yrow + l * 8);
    float yv[8];
#pragma unroll
    for (int j = 0; j < 8; ++j) yv[j] = bits2f(y1[j]);
    float s5[5];
#pragma unroll
    for (int cc = 0; cc < 5; ++cc) {
        f4 wa = *(const f4*)(W2T + cc * 512 + l * 8);
        f4 wb = *(const f4*)(W2T + cc * 512 + l * 8 + 4);
        float a = 0.f;
#pragma unroll
        for (int j = 0; j < 4; ++j) a += yv[j] * wa[j];
#pragma unroll
        for (int j = 0; j < 4; ++j) a += yv[4 + j] * wb[j];
        s5[cc] = a;
    }
#pragma unroll
    for (int cc = 0; cc < 5; ++cc) s5[cc] = wsum(s5[cc]) + b2[cc];
    float mx = s5[0];
#pragma unroll
    for (int cc = 1; cc < 5; ++cc) mx = fmaxf(mx, s5[cc]);
    float ct[5]; float den = 0.f;
#pragma unroll
    for (int cc = 0; cc < 5; ++cc) { ct[cc] = expf(s5[cc] - mx); den += ct[cc]; }
    float inv = 1.f / den;
#pragma unroll
    for (int cc = 0; cc < 5; ++cc) ct[cc] *= inv;
    if (l < 5) out_ct[r * 5 + l] = ct[l];
    if (l == 0) out_rel[r] = 1.f - ct[3];

    // ---- bias path (be2) ----
    short4v y3 = *(const short4v*)(yrow + 512 + l * 4);
    f4 wv = *(const f4*)(Wbe + l * 4);
    float sb = 0.f;
#pragma unroll
    for (int j = 0; j < 4; ++j) sb += bits2f(y3[j]) * wv[j];
    sb = wsum(sb);
    if (l == 0) {
        float sig = 1.f / (1.f + expf(-(sb + bbe[0])));
        float cb = 0.1f * ct[0] + 1.0f * ct[1] + 0.8f * ct[2] + 0.3f * ct[3] + 0.5f * ct[4];
        out_wb[r] = sig * cb;
    }

    // ---- credibility (cr2, rank-5 ct correction + relu + dot) ----
    short8 y4 = *(const short8*)(yrow + 768 + l * 8);
    float corr[8] = {0, 0, 0, 0, 0, 0, 0, 0};
#pragma unroll
    for (int cc = 0; cc < 5; ++cc) {
        f4 a = *(const f4*)(W5 + cc * 512 + l * 8);
        f4 b = *(const f4*)(W5 + cc * 512 + l * 8 + 4);
#pragma unroll
        for (int j = 0; j < 4; ++j) { corr[j] += ct[cc] * a[j]; corr[4 + j] += ct[cc] * b[j]; }
    }
    f4 wca = *(const f4*)(Wcr + l * 8);
    f4 wcb = *(const f4*)(Wcr + l * 8 + 4);
    float scr = 0.f;
#pragma unroll
    for (int j = 0; j < 4; ++j) scr += fmaxf(bits2f(y4[j]) + corr[j], 0.f) * wca[j];
#pragma unroll
    for (int j = 0; j < 4; ++j) scr += fmaxf(bits2f(y4[4 + j]) + corr[4 + j], 0.f) * wcb[j];
    scr = wsum(scr);
    if (l == 0) out_cred[r] = 1.f / (1.f + expf(-(scr + bcr[0])));

    // ---- LN + gelu + cd2 (lane owns elements l*8 + c*512, c=0,1) ----
    const bf16* hrow = H + r * 1024;
    float v[16];
    float sum = 0.f, sum2 = 0.f;
#pragma unroll
    for (int c = 0; c < 2; ++c) {
        short8 hh = *(const short8*)(hrow + c * 512 + l * 8);
#pragma unroll
        for (int j = 0; j < 8; ++j) {
            float f = bits2f(hh[j]);
            v[c * 8 + j] = f;
            sum += f; sum2 += f * f;
        }
    }
    sum = wsum(sum);
    sum2 = wsum(sum2);
    float mu = sum * (1.f / 1024.f);
    float var = sum2 * (1.f / 1024.f) - mu * mu;
    float rstd = rsqrtf(var + 1e-5f);
    float dot = 0.f;
#pragma unroll
    for (int c = 0; c < 2; ++c) {
        int base = c * 512 + l * 8;
        f4 ga = *(const f4*)(g + base),  gb = *(const f4*)(g + base + 4);
        f4 ba = *(const f4*)(be + base), bb = *(const f4*)(be + base + 4);
        f4 wa = *(const f4*)(Wd + base), wb = *(const f4*)(Wd + base + 4);
#pragma unroll
        for (int j = 0; j < 4; ++j) {
            float hn = (v[c * 8 + j] - mu) * rstd * ga[j] + ba[j];
            float ge = 0.5f * hn * (1.f + erff(hn * 0.70710678118654752f));
            dot += ge * wa[j];
            float hn2 = (v[c * 8 + 4 + j] - mu) * rstd * gb[j] + bb[j];
            float ge2 = 0.5f * hn2 * (1.f + erff(hn2 * 0.70710678118654752f));
            dot += ge2 * wb[j];
        }
    }
    dot = wsum(dot);
    if (l == 0) {
        float contr = 1.f / (1.f + expf(-(dot + bd[0])));
        out_enh[r] = fmaxf(contr, ct[2]);
    }
}

extern "C" void kernel_launch(void* const* d_in, const int* in_sizes, int n_in,
                              void* d_out, int out_size, void* d_ws, size_t ws_size,
                              hipStream_t stream) {
    const float* x      = (const float*)d_in[0];
    const float* W_cc1  = (const float*)d_in[1];
    const float* b_cc1  = (const float*)d_in[2];
    const float* W_cc2  = (const float*)d_in[3];
    const float* b_cc2  = (const float*)d_in[4];
    const float* W_cd1  = (const float*)d_in[5];
    const float* b_cd1  = (const float*)d_in[6];
    const float* g_ln   = (const float*)d_in[7];
    const float* be_ln  = (const float*)d_in[8];
    const float* W_cd2  = (const float*)d_in[9];
    const float* b_cd2  = (const float*)d_in[10];
    const float* W_be1  = (const float*)d_in[11];
    const float* b_be1  = (const float*)d_in[12];
    const float* W_be2  = (const float*)d_in[13];
    const float* b_be2  = (const float*)d_in[14];
    const float* W_cr1  = (const float*)d_in[15];
    const float* b_cr1  = (const float*)d_in[16];
    const float* W_cr2  = (const float*)d_in[17];
    const float* b_cr2  = (const float*)d_in[18];

    float* out = (float*)d_out;
    float* out_x    = out;
    float* out_ct   = out_x + (long)ROWS * D;
    float* out_enh  = out_ct + ROWS * 5;
    float* out_wb   = out_enh + ROWS;
    float* out_rel  = out_wb + ROWS;
    float* out_cred = out_rel + ROWS;

    char* cur = (char*)d_ws;
    auto alloc = [&](size_t bytes) { char* p = cur; cur += (bytes + 255) & ~(size_t)255; return p; };

    bf16* WT1    = (bf16*)alloc((size_t)N1 * 1024 * 2);     // [1280][1024]
    bf16* WT2    = (bf16*)alloc((size_t)1024 * 2048 * 2);   // [1024][2048] cd1 full
    float* W2T   = (float*)alloc((size_t)5 * 512 * 4);
    float* biasA = (float*)alloc((size_t)N1 * 4);
    bf16* xb     = (bf16*)alloc((size_t)ROWS * 1024 * 2);
    bf16* ctxb   = (bf16*)alloc((size_t)ROWS * 1024 * 2);
    bf16* YB     = (bf16*)alloc((size_t)ROWS * N1 * 2);     // 40 MB
    bf16* Hbuf   = (bf16*)alloc((size_t)ROWS * 1024 * 2);   // 32 MB
    float* part  = (float*)alloc((size_t)Bb * 16 * 1024 * 4);
    float* totl  = (float*)alloc((size_t)Bb * 1024 * 4);

    // weight prep (tiled transpose fp32->bf16, B^T k-contiguous)
    transpose_tiled<<<dim3(8, 16), 256, 0, stream>>>(W_cc1, 512, 0, 0, WT1, 1024, 0);
    transpose_tiled<<<dim3(4, 16), 256, 0, stream>>>(W_be1, 256, 0, 0, WT1, 1024, (long)512 * 1024);
    transpose_tiled<<<dim3(8, 16), 256, 0, stream>>>(W_cr1, 512, 0, 0, WT1, 1024, (long)768 * 1024);
    transpose_tiled<<<dim3(16, 32), 256, 0, stream>>>(W_cd1, 1024, 0, 0, WT2, 2048, 0);
    prep_w2t<<<10, 256, 0, stream>>>(W_cc2, W2T);
    build_bias<<<(N1 + 255) / 256, 256, 0, stream>>>(b_cc1, b_be1, b_cr1, biasA);

    // ctx scan (emits xb bf16 + ctx bf16 + exact fp32 x passthrough)
    scan_partial<<<dim3(4, 16, 8), 256, 0, stream>>>(x, part);
    scan_offsets<<<32, 256, 0, stream>>>(part, totl);
    scan_ctx<<<dim3(4, 16, 8), 256, 0, stream>>>(x, part, totl, ctxb, xb, out_x);

    // GEMM-1: YB[16384][1280] = xb @ WT1^T + biasA (relu on cols < 768)
    gemm_bt<<<dim3(N1 / 128, ROWS / 128), 256, 0, stream>>>(
        xb, xb, 1024, 1024, WT1, biasA, YB, N1, 1024, 768, 1);
    // GEMM-2: Hbuf[16384][1024] = [xb | ctxb] @ WT2^T + b_cd1 (split-A, K=2048)
    gemm_bt<<<dim3(1024 / 128, ROWS / 128), 256, 0, stream>>>(
        xb, ctxb, 1024, 1024, WT2, b_cd1, Hbuf, 1024, 2048, 0, 1);

    // fused epilogue (softmax, be2, cr2, LN+gelu+cd2)
    epilogue<<<ROWS / 4, 256, 0, stream>>>(
        YB, Hbuf, W2T, b_cc2, W_be2, b_be2,
        W_cr1 + (long)1024 * 512, W_cr2, b_cr2,
        g_ln, be_ln, W_cd2, b_cd2,
        out_ct, out_enh, out_wb, out_rel, out_cred);

    (void)in_sizes; (void)n_in; (void)out_size; (void)ws_size;
}

// Round 5
// 408.373 us; speedup vs baseline: 1.3435x; 1.0325x over previous
//
#include <hip/hip_runtime.h>
#include <hip/hip_bf16.h>
#include <cstdint>

typedef __hip_bfloat16 bf16;
using short8 = __attribute__((ext_vector_type(8))) short;
using short4v = __attribute__((ext_vector_type(4))) short;
using f32x4  = __attribute__((ext_vector_type(4))) float;
using f4     = __attribute__((ext_vector_type(4))) float;

#define DEV __device__ __forceinline__

static constexpr int Bb = 8;
static constexpr int S  = 2048;
static constexpr int D  = 1024;
static constexpr long ROWS = (long)Bb * S;   // 16384
static constexpr int N1 = 1280;              // 512(cc1) + 256(be1) + 512(cr1-x)
static constexpr int MT = 128;               // row tiles = ROWS/128
static constexpr int CT1 = N1 / 128;         // 10 col tiles for GEMM-1 region
static constexpr int CT2 = 1024 / 128;       // 8 col tiles for cd1 region

DEV void async_copy16(const void* g, void* l) {
    __builtin_amdgcn_global_load_lds((const __attribute__((address_space(1))) void*)g,
                                     (__attribute__((address_space(3))) void*)l,
                                     16, 0, 0);
}

DEV float wsum(float v) {
#pragma unroll
    for (int off = 32; off > 0; off >>= 1) v += __shfl_xor(v, off, 64);
    return v;
}

DEV float bf2f(bf16 x) { return __bfloat162float(x); }
DEV bf16  f2bf(float x) { return __float2bfloat16(x); }
DEV float bits2f(short s) {
    unsigned u = ((unsigned)(unsigned short)s) << 16;
    float f; __builtin_memcpy(&f, &u, 4); return f;
}

// -------- LDS-tiled transpose+cast: dst[n][k] = W[row0+k][col0+n], 64x64 tiles --------
__global__ __launch_bounds__(256) void transpose_tiled(
    const float* __restrict__ W, int ldw, int row0, int col0,
    bf16* __restrict__ dst, long dstLd, long dstOff)
{
    __shared__ float tile[64][65];
    const int t = threadIdx.x, tx = t & 63, ty = t >> 6;
    const int kt = blockIdx.y * 64, nt = blockIdx.x * 64;
#pragma unroll
    for (int p = 0; p < 16; ++p) {
        int k = ty * 16 + p;
        tile[k][tx] = W[(long)(row0 + kt + k) * ldw + col0 + nt + tx];
    }
    __syncthreads();
#pragma unroll
    for (int p = 0; p < 16; ++p) {
        int n = ty * 16 + p;
        dst[dstOff + (long)(nt + n) * dstLd + kt + tx] = f2bf(tile[tx][n]);
    }
}

// -------- W_cc2 (512x5) -> W2T (5x512) fp32, tiny --------
__global__ void prep_w2t(const float* __restrict__ W2, float* __restrict__ W2T) {
    int i = blockIdx.x * 256 + threadIdx.x;
    if (i >= 2560) return;
    int cc = i >> 9, n = i & 511;
    W2T[i] = W2[(long)n * 5 + cc];
}

// -------- concat biases into biasAll[1280] --------
__global__ void build_bias(const float* __restrict__ b1, const float* __restrict__ b2,
                           const float* __restrict__ b3, float* __restrict__ o) {
    int i = blockIdx.x * 256 + threadIdx.x;
    if (i >= N1) return;
    float v;
    if (i < 512)       v = b1[i];
    else if (i < 768)  v = b2[i - 512];
    else               v = b3[i - 768];
    o[i] = v;
}

// -------- scan phase A: per-chunk partial sums --------
__global__ void scan_partial(const float* __restrict__ x, float* __restrict__ part) {
    int d = blockIdx.x * 256 + threadIdx.x;
    int c = blockIdx.y, b = blockIdx.z;
    const float* p = x + ((long)b * S + (long)c * 128) * D + d;
    float s = 0.f;
#pragma unroll 8
    for (int j = 0; j < 128; ++j) s += p[(long)j * D];
    part[((long)(b * 16 + c)) * D + d] = s;
}

// -------- scan phase B: exclusive scan over 16 chunks + total --------
__global__ void scan_offsets(float* __restrict__ part, float* __restrict__ total) {
    int idx = blockIdx.x * 256 + threadIdx.x;   // 8192
    int b = idx >> 10, d = idx & 1023;
    float* p = part + (long)(b * 16) * D + d;
    float run = 0.f;
#pragma unroll
    for (int c = 0; c < 16; ++c) { float v = p[(long)c * D]; p[(long)c * D] = run; run += v; }
    total[idx] = run;
}

// -------- scan phase C: emit ctx (bf16), xb (bf16), exact fp32 x passthrough --------
__global__ void scan_ctx(const float* __restrict__ x, const float* __restrict__ part,
                         const float* __restrict__ total, bf16* __restrict__ ctxb,
                         bf16* __restrict__ xb, float* __restrict__ outx) {
    int d = blockIdx.x * 256 + threadIdx.x;
    int c = blockIdx.y, b = blockIdx.z;
    float run = part[((long)(b * 16 + c)) * D + d];
    float tot = total[(long)b * D + d];
    const long base = ((long)b * S + (long)c * 128) * D + d;
    const float* px = x + base;
    bf16* pc = ctxb + base;
    bf16* pb = xb + base;
    float* po = outx + base;
    for (int j = 0; j < 128; ++j) {
        int s = c * 128 + j;
        float xv = px[(long)j * D];
        float ctxv;
        if (s == 0 || s == S - 1) {
            ctxv = (tot - xv) * (1.0f / (float)(S - 1));
        } else {
            ctxv = 0.5f * (run / (float)s + (tot - run - xv) / (float)(S - 1 - s));
        }
        pc[(long)j * D] = f2bf(ctxv);
        pb[(long)j * D] = f2bf(xv);
        po[(long)j * D] = xv;           // exact fp32 copy
        run += xv;
    }
}

// -------- merged MFMA GEMM (XOR-swizzled LDS, XCD-aware block order) --------
// 1D grid of (CT1+CT2)*MT blocks. bid -> col_t = bid/MT, row_t = bid%MT:
// same-row-panel blocks differ by MT==128 (=0 mod 8) -> same XCD -> A-panel L2 reuse.
//   col_t <  CT1: O1[row][col] = relu?(xb @ WT1^T + biasA), K=1024
//   col_t >= CT1: O2[row][col'] = [xb|ctxb] @ WT2^T + biasC, K=2048
__global__ __launch_bounds__(256) void gemm_merged(
    const bf16* __restrict__ Axb, const bf16* __restrict__ Actx,
    const bf16* __restrict__ WT1, const bf16* __restrict__ WT2,
    const float* __restrict__ biasA, const float* __restrict__ biasC,
    bf16* __restrict__ O1, bf16* __restrict__ O2)
{
    __shared__ __align__(16) bf16 ldsA[128 * 64];
    __shared__ __align__(16) bf16 ldsB[128 * 64];

    const int bid = blockIdx.x;
    const int col_t = bid / MT, row_t = bid % MT;
    const int row0 = row_t * 128;
    const bool g1 = (col_t < CT1);
    const int col0 = g1 ? col_t * 128 : (col_t - CT1) * 128;
    const int K    = g1 ? 1024 : 2048;
    const int ldb  = g1 ? 1024 : 2048;
    const bf16* BT = g1 ? (WT1 + (long)col0 * 1024) : (WT2 + (long)col0 * 2048);

    const int tid = threadIdx.x;
    const int w = tid >> 6, l = tid & 63;
    const int wm = (w >> 1) * 64, wn = (w & 1) * 64;

    f32x4 acc[4][4];
#pragma unroll
    for (int i = 0; i < 4; ++i)
#pragma unroll
        for (int j = 0; j < 4; ++j) acc[i][j] = (f32x4){0.f, 0.f, 0.f, 0.f};

    const int lr = l >> 3;                       // row within 8-row group
    const int cb = l & 7;                        // destination kblock slot
    const int ksrc = ((cb ^ lr) << 3);           // swizzled source k offset (elements)

    const int lm = l & 15, lq = l >> 4;
    const int rsw = lm & 7;                      // row&7 for swizzle inversion

    for (int k0 = 0; k0 < K; k0 += 64) {
        const bf16* Ab = (k0 < 1024) ? Axb : Actx;
        const int kk = (k0 < 1024) ? k0 : k0 - 1024;
#pragma unroll
        for (int i = 0; i < 4; ++i) {
            int r = w * 32 + i * 8;
            async_copy16(Ab + (long)(row0 + r + lr) * 1024 + kk + ksrc, &ldsA[r * 64]);
            async_copy16(BT + (long)(r + lr) * ldb + k0 + ksrc, &ldsB[r * 64]);
        }
        __syncthreads();
#pragma unroll
        for (int h = 0; h < 2; ++h) {
            const int slot = ((h * 4 + lq) ^ rsw) << 3;
            short8 af[4], bfr[4];
#pragma unroll
            for (int i = 0; i < 4; ++i)
                af[i] = *(const short8*)&ldsA[(wm + i * 16 + lm) * 64 + slot];
#pragma unroll
            for (int j = 0; j < 4; ++j)
                bfr[j] = *(const short8*)&ldsB[(wn + j * 16 + lm) * 64 + slot];
#pragma unroll
            for (int i = 0; i < 4; ++i)
#pragma unroll
                for (int j = 0; j < 4; ++j)
                    acc[i][j] = __builtin_amdgcn_mfma_f32_16x16x32_bf16(af[i], bfr[j], acc[i][j], 0, 0, 0);
        }
        __syncthreads();
    }

    bf16* O = g1 ? O1 : O2;
    const long ldo = g1 ? N1 : 1024;
    const float* bias = g1 ? biasA : biasC;
    const int reluN = g1 ? 768 : 0;

#pragma unroll
    for (int j = 0; j < 4; ++j) {
        int col = col0 + wn + j * 16 + lm;
        float bv = bias[col];
        bool rl = col < reluN;
#pragma unroll
        for (int i = 0; i < 4; ++i) {
#pragma unroll
            for (int r = 0; r < 4; ++r) {
                int row = row0 + wm + i * 16 + lq * 4 + r;
                float v = acc[i][j][r] + bv;
                if (rl) v = fmaxf(v, 0.f);
                O[(long)row * ldo + col] = f2bf(v);
            }
        }
    }
}

// -------- fused epilogue: softmax + be2 + cr2 + LN/gelu/cd2, wave per row --------
__global__ __launch_bounds__(256) void epilogue(
    const bf16* __restrict__ YB, const bf16* __restrict__ H,
    const float* __restrict__ W2T, const float* __restrict__ b2,
    const float* __restrict__ Wbe, const float* __restrict__ bbe,
    const float* __restrict__ W5, const float* __restrict__ Wcr, const float* __restrict__ bcr,
    const float* __restrict__ g, const float* __restrict__ be,
    const float* __restrict__ Wd, const float* __restrict__ bd,
    float* __restrict__ out_ct, float* __restrict__ out_enh, float* __restrict__ out_wb,
    float* __restrict__ out_rel, float* __restrict__ out_cred)
{
    const int w = threadIdx.x >> 6, l = threadIdx.x & 63;
    const long r = (long)blockIdx.x * 4 + w;
    const bf16* yrow = YB + r * N1;

    // ---- content-type softmax (cc2) ----
    short8 y1 = *(const short8*)(yrow + l * 8);
    float yv[8];
#pragma unroll
    for (int j = 0; j < 8; ++j) yv[j] = bits2f(y1[j]);
    float s5[5];
#pragma unroll
    for (int cc = 0; cc < 5; ++cc) {
        f4 wa = *(const f4*)(W2T + cc * 512 + l * 8);
        f4 wb = *(const f4*)(W2T + cc * 512 + l * 8 + 4);
        float a = 0.f;
#pragma unroll
        for (int j = 0; j < 4; ++j) a += yv[j] * wa[j];
#pragma unroll
        for (int j = 0; j < 4; ++j) a += yv[4 + j] * wb[j];
        s5[cc] = a;
    }
#pragma unroll
    for (int cc = 0; cc < 5; ++cc) s5[cc] = wsum(s5[cc]) + b2[cc];
    float mx = s5[0];
#pragma unroll
    for (int cc = 1; cc < 5; ++cc) mx = fmaxf(mx, s5[cc]);
    float ct[5]; float den = 0.f;
#pragma unroll
    for (int cc = 0; cc < 5; ++cc) { ct[cc] = expf(s5[cc] - mx); den += ct[cc]; }
    float inv = 1.f / den;
#pragma unroll
    for (int cc = 0; cc < 5; ++cc) ct[cc] *= inv;
    if (l < 5) out_ct[r * 5 + l] = ct[l];
    if (l == 0) out_rel[r] = 1.f - ct[3];

    // ---- bias path (be2) ----
    short4v y3 = *(const short4v*)(yrow + 512 + l * 4);
    f4 wv = *(const f4*)(Wbe + l * 4);
    float sb = 0.f;
#pragma unroll
    for (int j = 0; j < 4; ++j) sb += bits2f(y3[j]) * wv[j];
    sb = wsum(sb);
    if (l == 0) {
        float sig = 1.f / (1.f + expf(-(sb + bbe[0])));
        float cb = 0.1f * ct[0] + 1.0f * ct[1] + 0.8f * ct[2] + 0.3f * ct[3] + 0.5f * ct[4];
        out_wb[r] = sig * cb;
    }

    // ---- credibility (cr2, rank-5 ct correction + relu + dot) ----
    short8 y4 = *(const short8*)(yrow + 768 + l * 8);
    float corr[8] = {0, 0, 0, 0, 0, 0, 0, 0};
#pragma unroll
    for (int cc = 0; cc < 5; ++cc) {
        f4 a = *(const f4*)(W5 + cc * 512 + l * 8);
        f4 b = *(const f4*)(W5 + cc * 512 + l * 8 + 4);
#pragma unroll
        for (int j = 0; j < 4; ++j) { corr[j] += ct[cc] * a[j]; corr[4 + j] += ct[cc] * b[j]; }
    }
    f4 wca = *(const f4*)(Wcr + l * 8);
    f4 wcb = *(const f4*)(Wcr + l * 8 + 4);
    float scr = 0.f;
#pragma unroll
    for (int j = 0; j < 4; ++j) scr += fmaxf(bits2f(y4[j]) + corr[j], 0.f) * wca[j];
#pragma unroll
    for (int j = 0; j < 4; ++j) scr += fmaxf(bits2f(y4[4 + j]) + corr[4 + j], 0.f) * wcb[j];
    scr = wsum(scr);
    if (l == 0) out_cred[r] = 1.f / (1.f + expf(-(scr + bcr[0])));

    // ---- LN + gelu + cd2 (lane owns elements l*8 + c*512, c=0,1) ----
    const bf16* hrow = H + r * 1024;
    float v[16];
    float sum = 0.f, sum2 = 0.f;
#pragma unroll
    for (int c = 0; c < 2; ++c) {
        short8 hh = *(const short8*)(hrow + c * 512 + l * 8);
#pragma unroll
        for (int j = 0; j < 8; ++j) {
            float f = bits2f(hh[j]);
            v[c * 8 + j] = f;
            sum += f; sum2 += f * f;
        }
    }
    sum = wsum(sum);
    sum2 = wsum(sum2);
    float mu = sum * (1.f / 1024.f);
    float var = sum2 * (1.f / 1024.f) - mu * mu;
    float rstd = rsqrtf(var + 1e-5f);
    float dot = 0.f;
#pragma unroll
    for (int c = 0; c < 2; ++c) {
        int base = c * 512 + l * 8;
        f4 ga = *(const f4*)(g + base),  gb = *(const f4*)(g + base + 4);
        f4 ba = *(const f4*)(be + base), bb = *(const f4*)(be + base + 4);
        f4 wa = *(const f4*)(Wd + base), wb = *(const f4*)(Wd + base + 4);
#pragma unroll
        for (int j = 0; j < 4; ++j) {
            float hn = (v[c * 8 + j] - mu) * rstd * ga[j] + ba[j];
            float ge = 0.5f * hn * (1.f + erff(hn * 0.70710678118654752f));
            dot += ge * wa[j];
            float hn2 = (v[c * 8 + 4 + j] - mu) * rstd * gb[j] + bb[j];
            float ge2 = 0.5f * hn2 * (1.f + erff(hn2 * 0.70710678118654752f));
            dot += ge2 * wb[j];
        }
    }
    dot = wsum(dot);
    if (l == 0) {
        float contr = 1.f / (1.f + expf(-(dot + bd[0])));
        out_enh[r] = fmaxf(contr, ct[2]);
    }
}

extern "C" void kernel_launch(void* const* d_in, const int* in_sizes, int n_in,
                              void* d_out, int out_size, void* d_ws, size_t ws_size,
                              hipStream_t stream) {
    const float* x      = (const float*)d_in[0];
    const float* W_cc1  = (const float*)d_in[1];
    const float* b_cc1  = (const float*)d_in[2];
    const float* W_cc2  = (const float*)d_in[3];
    const float* b_cc2  = (const float*)d_in[4];
    const float* W_cd1  = (const float*)d_in[5];
    const float* b_cd1  = (const float*)d_in[6];
    const float* g_ln   = (const float*)d_in[7];
    const float* be_ln  = (const float*)d_in[8];
    const float* W_cd2  = (const float*)d_in[9];
    const float* b_cd2  = (const float*)d_in[10];
    const float* W_be1  = (const float*)d_in[11];
    const float* b_be1  = (const float*)d_in[12];
    const float* W_be2  = (const float*)d_in[13];
    const float* b_be2  = (const float*)d_in[14];
    const float* W_cr1  = (const float*)d_in[15];
    const float* b_cr1  = (const float*)d_in[16];
    const float* W_cr2  = (const float*)d_in[17];
    const float* b_cr2  = (const float*)d_in[18];

    float* out = (float*)d_out;
    float* out_x    = out;
    float* out_ct   = out_x + (long)ROWS * D;
    float* out_enh  = out_ct + ROWS * 5;
    float* out_wb   = out_enh + ROWS;
    float* out_rel  = out_wb + ROWS;
    float* out_cred = out_rel + ROWS;

    char* cur = (char*)d_ws;
    auto alloc = [&](size_t bytes) { char* p = cur; cur += (bytes + 255) & ~(size_t)255; return p; };

    bf16* WT1    = (bf16*)alloc((size_t)N1 * 1024 * 2);     // [1280][1024]
    bf16* WT2    = (bf16*)alloc((size_t)1024 * 2048 * 2);   // [1024][2048] cd1 full
    float* W2T   = (float*)alloc((size_t)5 * 512 * 4);
    float* biasA = (float*)alloc((size_t)N1 * 4);
    bf16* xb     = (bf16*)alloc((size_t)ROWS * 1024 * 2);
    bf16* ctxb   = (bf16*)alloc((size_t)ROWS * 1024 * 2);
    bf16* YB     = (bf16*)alloc((size_t)ROWS * N1 * 2);     // 40 MB
    bf16* Hbuf   = (bf16*)alloc((size_t)ROWS * 1024 * 2);   // 32 MB
    float* part  = (float*)alloc((size_t)Bb * 16 * 1024 * 4);
    float* totl  = (float*)alloc((size_t)Bb * 1024 * 4);

    // weight prep (tiled transpose fp32->bf16, B^T k-contiguous)
    transpose_tiled<<<dim3(8, 16), 256, 0, stream>>>(W_cc1, 512, 0, 0, WT1, 1024, 0);
    transpose_tiled<<<dim3(4, 16), 256, 0, stream>>>(W_be1, 256, 0, 0, WT1, 1024, (long)512 * 1024);
    transpose_tiled<<<dim3(8, 16), 256, 0, stream>>>(W_cr1, 512, 0, 0, WT1, 1024, (long)768 * 1024);
    transpose_tiled<<<dim3(16, 32), 256, 0, stream>>>(W_cd1, 1024, 0, 0, WT2, 2048, 0);
    prep_w2t<<<10, 256, 0, stream>>>(W_cc2, W2T);
    build_bias<<<(N1 + 255) / 256, 256, 0, stream>>>(b_cc1, b_be1, b_cr1, biasA);

    // ctx scan (emits xb bf16 + ctx bf16 + exact fp32 x passthrough)
    scan_partial<<<dim3(4, 16, 8), 256, 0, stream>>>(x, part);
    scan_offsets<<<32, 256, 0, stream>>>(part, totl);
    scan_ctx<<<dim3(4, 16, 8), 256, 0, stream>>>(x, part, totl, ctxb, xb, out_x);

    // merged GEMM: col tiles 0-9 -> YB (N=1280, K=1024, relu<768, biasA);
    //              col tiles 10-17 -> Hbuf (N=1024, K=2048 split-A, b_cd1)
    gemm_merged<<<dim3((CT1 + CT2) * MT), 256, 0, stream>>>(
        xb, ctxb, WT1, WT2, biasA, b_cd1, YB, Hbuf);

    // fused epilogue (softmax, be2, cr2, LN+gelu+cd2)
    epilogue<<<ROWS / 4, 256, 0, stream>>>(
        YB, Hbuf, W2T, b_cc2, W_be2, b_be2,
        W_cr1 + (long)1024 * 512, W_cr2, b_cr2,
        g_ln, be_ln, W_cd2, b_cd2,
        out_ct, out_enh, out_wb, out_rel, out_cred);

    (void)in_sizes; (void)n_in; (void)out_size; (void)ws_size;
}

// Round 6
// 379.763 us; speedup vs baseline: 1.4447x; 1.0753x over previous
//
#include <hip/hip_runtime.h>
#include <hip/hip_bf16.h>
#include <cstdint>

typedef __hip_bfloat16 bf16;
using short8 = __attribute__((ext_vector_type(8))) short;
using short4v = __attribute__((ext_vector_type(4))) short;
using f32x4  = __attribute__((ext_vector_type(4))) float;
using f4     = __attribute__((ext_vector_type(4))) float;

#define DEV __device__ __forceinline__

static constexpr int Bb = 8;
static constexpr int S  = 2048;
static constexpr int D  = 1024;
static constexpr long ROWS = (long)Bb * S;   // 16384
static constexpr int N1 = 1280;              // 512(cc1) + 256(be1) + 512(cr1-x)
static constexpr int MT = 128;               // row tiles = ROWS/128
static constexpr int CT1 = N1 / 128;         // 10 col tiles for GEMM-1 region
static constexpr int CT2 = 1024 / 128;       // 8 col tiles for cd1 region
static constexpr int NCH = 64;               // scan chunks (32 rows each)

DEV void async_copy16(const void* g, void* l) {
    __builtin_amdgcn_global_load_lds((const __attribute__((address_space(1))) void*)g,
                                     (__attribute__((address_space(3))) void*)l,
                                     16, 0, 0);
}

DEV float wsum(float v) {
#pragma unroll
    for (int off = 32; off > 0; off >>= 1) v += __shfl_xor(v, off, 64);
    return v;
}

DEV float bf2f(bf16 x) { return __bfloat162float(x); }
DEV bf16  f2bf(float x) { return __float2bfloat16(x); }
DEV short f2bfbits(float v) { bf16 h = f2bf(v); short s; __builtin_memcpy(&s, &h, 2); return s; }
DEV float bits2f(short s) {
    unsigned u = ((unsigned)(unsigned short)s) << 16;
    float f; __builtin_memcpy(&f, &u, 4); return f;
}

// -------- single prep kernel: 4 tiled transposes (fp32->bf16 B^T) + W2T + bias concat ------
// tiles: [0,128) cc1 | [128,192) be1 | [192,320) cr1 | [320,832) cd1 | 832 small stuff
__global__ __launch_bounds__(256) void prep_all(
    const float* __restrict__ Wcc1, const float* __restrict__ Wbe1,
    const float* __restrict__ Wcr1, const float* __restrict__ Wcd1,
    const float* __restrict__ Wcc2,
    const float* __restrict__ b1, const float* __restrict__ b2, const float* __restrict__ b3,
    bf16* __restrict__ WT1, bf16* __restrict__ WT2,
    float* __restrict__ W2T, float* __restrict__ biasA)
{
    const int bid = blockIdx.x, t = threadIdx.x;
    if (bid == 832) {
        for (int i = t; i < 2560; i += 256) {
            int cc = i >> 9, n = i & 511;
            W2T[i] = Wcc2[(long)n * 5 + cc];
        }
        for (int i = t; i < N1; i += 256) {
            float v;
            if (i < 512)       v = b1[i];
            else if (i < 768)  v = b2[i - 512];
            else               v = b3[i - 768];
            biasA[i] = v;
        }
        return;
    }
    const float* W; int ldw; bf16* dst; long dstLd, dstOff; int nt, kt;
    if (bid < 128)      { W = Wcc1; ldw = 512;  dst = WT1; dstLd = 1024; dstOff = 0;
                          nt = bid & 7; kt = bid >> 3; }
    else if (bid < 192) { W = Wbe1; ldw = 256;  dst = WT1; dstLd = 1024; dstOff = (long)512 * 1024;
                          int lb = bid - 128; nt = lb & 3; kt = lb >> 2; }
    else if (bid < 320) { W = Wcr1; ldw = 512;  dst = WT1; dstLd = 1024; dstOff = (long)768 * 1024;
                          int lb = bid - 192; nt = lb & 7; kt = lb >> 3; }
    else                { W = Wcd1; ldw = 1024; dst = WT2; dstLd = 2048; dstOff = 0;
                          int lb = bid - 320; nt = lb & 15; kt = lb >> 4; }

    __shared__ float tile[64][65];
    const int tx = t & 63, ty = t >> 6;
    const int k64 = kt * 64, n64 = nt * 64;
#pragma unroll
    for (int p = 0; p < 16; ++p) {
        int k = ty * 16 + p;
        tile[k][tx] = W[(long)(k64 + k) * ldw + n64 + tx];
    }
    __syncthreads();
#pragma unroll
    for (int p = 0; p < 16; ++p) {
        int n = ty * 16 + p;
        dst[dstOff + (long)(n64 + n) * dstLd + k64 + tx] = f2bf(tile[tx][n]);
    }
}

// -------- scan phase A: per-chunk partial sums, float4 lanes (chunk = 32 rows) --------
// grid: (NCH, Bb), 256 threads; lane t owns d = 4t..4t+3
__global__ __launch_bounds__(256) void scan_partial4(const float* __restrict__ x,
                                                     float* __restrict__ part) {
    const int t = threadIdx.x, c = blockIdx.x, b = blockIdx.y;
    const float* p = x + ((long)b * S + (long)c * 32) * D + t * 4;
    f4 s = {0.f, 0.f, 0.f, 0.f};
#pragma unroll 8
    for (int j = 0; j < 32; ++j) {
        f4 v = *(const f4*)(p + (long)j * D);
        s += v;
    }
    *(f4*)(part + ((long)(b * NCH + c)) * D + t * 4) = s;
}

// -------- scan phase B: exclusive scan over NCH chunks + total, grouped prefetch --------
__global__ void scan_offsets2(float* __restrict__ part, float* __restrict__ total) {
    int idx = blockIdx.x * 256 + threadIdx.x;   // 8192
    int b = idx >> 10, d = idx & 1023;
    float* p = part + (long)b * NCH * D + d;
    float run = 0.f;
#pragma unroll
    for (int g = 0; g < NCH / 8; ++g) {
        float v[8];
#pragma unroll
        for (int u = 0; u < 8; ++u) v[u] = p[(long)(g * 8 + u) * D];
#pragma unroll
        for (int u = 0; u < 8; ++u) { float tv = v[u]; p[(long)(g * 8 + u) * D] = run; run += tv; }
    }
    total[idx] = run;
}

// -------- scan phase C: emit ctx (bf16x4), xb (bf16x4), exact fp32 x passthrough --------
// grid: (NCH, Bb), 256 threads; lane t owns d = 4t..4t+3; 32 serial rows per chunk
__global__ __launch_bounds__(256) void scan_ctx4(
    const float* __restrict__ x, const float* __restrict__ part,
    const float* __restrict__ total, bf16* __restrict__ ctxb,
    bf16* __restrict__ xb, float* __restrict__ outx)
{
    const int t = threadIdx.x, c = blockIdx.x, b = blockIdx.y;
    const long col = (long)t * 4;
    f4 run = *(const f4*)(part + ((long)(b * NCH + c)) * D + col);
    const f4 tot = *(const f4*)(total + (long)b * D + col);
    const long base = ((long)b * S + (long)c * 32) * D + col;
    const float invE = 1.0f / (float)(S - 1);
#pragma unroll 4
    for (int j = 0; j < 32; ++j) {
        const int s = c * 32 + j;
        f4 xv = *(const f4*)(x + base + (long)j * D);
        f4 ctx;
        if (s == 0 || s == S - 1) {
#pragma unroll
            for (int e = 0; e < 4; ++e) ctx[e] = (tot[e] - xv[e]) * invE;
        } else {
            const float invp = 1.0f / (float)s, invs = 1.0f / (float)(S - 1 - s);
#pragma unroll
            for (int e = 0; e < 4; ++e)
                ctx[e] = 0.5f * (run[e] * invp + (tot[e] - run[e] - xv[e]) * invs);
        }
        *(f4*)(outx + base + (long)j * D) = xv;
        short4v cp, xp;
#pragma unroll
        for (int e = 0; e < 4; ++e) { cp[e] = f2bfbits(ctx[e]); xp[e] = f2bfbits(xv[e]); }
        *(short4v*)((short*)ctxb + base + (long)j * D) = cp;
        *(short4v*)((short*)xb + base + (long)j * D) = xp;
        run += xv;
    }
}

// -------- merged MFMA GEMM (XOR-swizzled LDS, XCD-aware block order) --------
// 1D grid of (CT1+CT2)*MT blocks. bid -> col_t = bid/MT, row_t = bid%MT:
// same-row-panel blocks differ by MT==128 (=0 mod 8) -> same XCD -> A-panel L2 reuse.
__global__ __launch_bounds__(256) void gemm_merged(
    const bf16* __restrict__ Axb, const bf16* __restrict__ Actx,
    const bf16* __restrict__ WT1, const bf16* __restrict__ WT2,
    const float* __restrict__ biasA, const float* __restrict__ biasC,
    bf16* __restrict__ O1, bf16* __restrict__ O2)
{
    __shared__ __align__(16) bf16 ldsA[128 * 64];
    __shared__ __align__(16) bf16 ldsB[128 * 64];

    const int bid = blockIdx.x;
    const int col_t = bid / MT, row_t = bid % MT;
    const int row0 = row_t * 128;
    const bool g1 = (col_t < CT1);
    const int col0 = g1 ? col_t * 128 : (col_t - CT1) * 128;
    const int K    = g1 ? 1024 : 2048;
    const int ldb  = g1 ? 1024 : 2048;
    const bf16* BT = g1 ? (WT1 + (long)col0 * 1024) : (WT2 + (long)col0 * 2048);

    const int tid = threadIdx.x;
    const int w = tid >> 6, l = tid & 63;
    const int wm = (w >> 1) * 64, wn = (w & 1) * 64;

    f32x4 acc[4][4];
#pragma unroll
    for (int i = 0; i < 4; ++i)
#pragma unroll
        for (int j = 0; j < 4; ++j) acc[i][j] = (f32x4){0.f, 0.f, 0.f, 0.f};

    const int lr = l >> 3;                       // row within 8-row group
    const int cb = l & 7;                        // destination kblock slot
    const int ksrc = ((cb ^ lr) << 3);           // swizzled source k offset (elements)

    const int lm = l & 15, lq = l >> 4;
    const int rsw = lm & 7;                      // row&7 for swizzle inversion

    for (int k0 = 0; k0 < K; k0 += 64) {
        const bf16* Ab = (k0 < 1024) ? Axb : Actx;
        const int kk = (k0 < 1024) ? k0 : k0 - 1024;
#pragma unroll
        for (int i = 0; i < 4; ++i) {
            int r = w * 32 + i * 8;
            async_copy16(Ab + (long)(row0 + r + lr) * 1024 + kk + ksrc, &ldsA[r * 64]);
            async_copy16(BT + (long)(r + lr) * ldb + k0 + ksrc, &ldsB[r * 64]);
        }
        __syncthreads();
#pragma unroll
        for (int h = 0; h < 2; ++h) {
            const int slot = ((h * 4 + lq) ^ rsw) << 3;
            short8 af[4], bfr[4];
#pragma unroll
            for (int i = 0; i < 4; ++i)
                af[i] = *(const short8*)&ldsA[(wm + i * 16 + lm) * 64 + slot];
#pragma unroll
            for (int j = 0; j < 4; ++j)
                bfr[j] = *(const short8*)&ldsB[(wn + j * 16 + lm) * 64 + slot];
#pragma unroll
            for (int i = 0; i < 4; ++i)
#pragma unroll
                for (int j = 0; j < 4; ++j)
                    acc[i][j] = __builtin_amdgcn_mfma_f32_16x16x32_bf16(af[i], bfr[j], acc[i][j], 0, 0, 0);
        }
        __syncthreads();
    }

    bf16* O = g1 ? O1 : O2;
    const long ldo = g1 ? N1 : 1024;
    const float* bias = g1 ? biasA : biasC;
    const int reluN = g1 ? 768 : 0;

#pragma unroll
    for (int j = 0; j < 4; ++j) {
        int col = col0 + wn + j * 16 + lm;
        float bv = bias[col];
        bool rl = col < reluN;
#pragma unroll
        for (int i = 0; i < 4; ++i) {
#pragma unroll
            for (int r = 0; r < 4; ++r) {
                int row = row0 + wm + i * 16 + lq * 4 + r;
                float v = acc[i][j][r] + bv;
                if (rl) v = fmaxf(v, 0.f);
                O[(long)row * ldo + col] = f2bf(v);
            }
        }
    }
}

// -------- fused epilogue: softmax + be2 + cr2 + LN/gelu/cd2, wave per row --------
__global__ __launch_bounds__(256) void epilogue(
    const bf16* __restrict__ YB, const bf16* __restrict__ H,
    const float* __restrict__ W2T, const float* __restrict__ b2,
    const float* __restrict__ Wbe, const float* __restrict__ bbe,
    const float* __restrict__ W5, const float* __restrict__ Wcr, const float* __restrict__ bcr,
    const float* __restrict__ g, const float* __restrict__ be,
    const float* __restrict__ Wd, const float* __restrict__ bd,
    float* __restrict__ out_ct, float* __restrict__ out_enh, float* __restrict__ out_wb,
    float* __restrict__ out_rel, float* __restrict__ out_cred)
{
    const int w = threadIdx.x >> 6, l = threadIdx.x & 63;
    const long r = (long)blockIdx.x * 4 + w;
    const bf16* yrow = YB + r * N1;

    // ---- content-type softmax (cc2) ----
    short8 y1 = *(const short8*)(yrow + l * 8);
    float yv[8];
#pragma unroll
    for (int j = 0; j < 8; ++j) yv[j] = bits2f(y1[j]);
    float s5[5];
#pragma unroll
    for (int cc = 0; cc < 5; ++cc) {
        f4 wa = *(const f4*)(W2T + cc * 512 + l * 8);
        f4 wb = *(const f4*)(W2T + cc * 512 + l * 8 + 4);
        float a = 0.f;
#pragma unroll
        for (int j = 0; j < 4; ++j) a += yv[j] * wa[j];
#pragma unroll
        for (int j = 0; j < 4; ++j) a += yv[4 + j] * wb[j];
        s5[cc] = a;
    }
#pragma unroll
    for (int cc = 0; cc < 5; ++cc) s5[cc] = wsum(s5[cc]) + b2[cc];
    float mx = s5[0];
#pragma unroll
    for (int cc = 1; cc < 5; ++cc) mx = fmaxf(mx, s5[cc]);
    float ct[5]; float den = 0.f;
#pragma unroll
    for (int cc = 0; cc < 5; ++cc) { ct[cc] = expf(s5[cc] - mx); den += ct[cc]; }
    float inv = 1.f / den;
#pragma unroll
    for (int cc = 0; cc < 5; ++cc) ct[cc] *= inv;
    if (l < 5) out_ct[r * 5 + l] = ct[l];
    if (l == 0) out_rel[r] = 1.f - ct[3];

    // ---- bias path (be2) ----
    short4v y3 = *(const short4v*)(yrow + 512 + l * 4);
    f4 wv = *(const f4*)(Wbe + l * 4);
    float sb = 0.f;
#pragma unroll
    for (int j = 0; j < 4; ++j) sb += bits2f(y3[j]) * wv[j];
    sb = wsum(sb);
    if (l == 0) {
        float sig = 1.f / (1.f + expf(-(sb + bbe[0])));
        float cb = 0.1f * ct[0] + 1.0f * ct[1] + 0.8f * ct[2] + 0.3f * ct[3] + 0.5f * ct[4];
        out_wb[r] = sig * cb;
    }

    // ---- credibility (cr2, rank-5 ct correction + relu + dot) ----
    short8 y4 = *(const short8*)(yrow + 768 + l * 8);
    float corr[8] = {0, 0, 0, 0, 0, 0, 0, 0};
#pragma unroll
    for (int cc = 0; cc < 5; ++cc) {
        f4 a = *(const f4*)(W5 + cc * 512 + l * 8);
        f4 b = *(const f4*)(W5 + cc * 512 + l * 8 + 4);
#pragma unroll
        for (int j = 0; j < 4; ++j) { corr[j] += ct[cc] * a[j]; corr[4 + j] += ct[cc] * b[j]; }
    }
    f4 wca = *(const f4*)(Wcr + l * 8);
    f4 wcb = *(const f4*)(Wcr + l * 8 + 4);
    float scr = 0.f;
#pragma unroll
    for (int j = 0; j < 4; ++j) scr += fmaxf(bits2f(y4[j]) + corr[j], 0.f) * wca[j];
#pragma unroll
    for (int j = 0; j < 4; ++j) scr += fmaxf(bits2f(y4[4 + j]) + corr[4 + j], 0.f) * wcb[j];
    scr = wsum(scr);
    if (l == 0) out_cred[r] = 1.f / (1.f + expf(-(scr + bcr[0])));

    // ---- LN + gelu + cd2 (lane owns elements l*8 + c*512, c=0,1) ----
    const bf16* hrow = H + r * 1024;
    float v[16];
    float sum = 0.f, sum2 = 0.f;
#pragma unroll
    for (int c = 0; c < 2; ++c) {
        short8 hh = *(const short8*)(hrow + c * 512 + l * 8);
#pragma unroll
        for (int j = 0; j < 8; ++j) {
            float f = bits2f(hh[j]);
            v[c * 8 + j] = f;
            sum += f; sum2 += f * f;
        }
    }
    sum = wsum(sum);
    sum2 = wsum(sum2);
    float mu = sum * (1.f / 1024.f);
    float var = sum2 * (1.f / 1024.f) - mu * mu;
    float rstd = rsqrtf(var + 1e-5f);
    float dot = 0.f;
#pragma unroll
    for (int c = 0; c < 2; ++c) {
        int base = c * 512 + l * 8;
        f4 ga = *(const f4*)(g + base),  gb = *(const f4*)(g + base + 4);
        f4 ba = *(const f4*)(be + base), bb = *(const f4*)(be + base + 4);
        f4 wa = *(const f4*)(Wd + base), wb = *(const f4*)(Wd + base + 4);
#pragma unroll
        for (int j = 0; j < 4; ++j) {
            float hn = (v[c * 8 + j] - mu) * rstd * ga[j] + ba[j];
            float ge = 0.5f * hn * (1.f + erff(hn * 0.70710678118654752f));
            dot += ge * wa[j];
            float hn2 = (v[c * 8 + 4 + j] - mu) * rstd * gb[j] + bb[j];
            float ge2 = 0.5f * hn2 * (1.f + erff(hn2 * 0.70710678118654752f));
            dot += ge2 * wb[j];
        }
    }
    dot = wsum(dot);
    if (l == 0) {
        float contr = 1.f / (1.f + expf(-(dot + bd[0])));
        out_enh[r] = fmaxf(contr, ct[2]);
    }
}

extern "C" void kernel_launch(void* const* d_in, const int* in_sizes, int n_in,
                              void* d_out, int out_size, void* d_ws, size_t ws_size,
                              hipStream_t stream) {
    const float* x      = (const float*)d_in[0];
    const float* W_cc1  = (const float*)d_in[1];
    const float* b_cc1  = (const float*)d_in[2];
    const float* W_cc2  = (const float*)d_in[3];
    const float* b_cc2  = (const float*)d_in[4];
    const float* W_cd1  = (const float*)d_in[5];
    const float* b_cd1  = (const float*)d_in[6];
    const float* g_ln   = (const float*)d_in[7];
    const float* be_ln  = (const float*)d_in[8];
    const float* W_cd2  = (const float*)d_in[9];
    const float* b_cd2  = (const float*)d_in[10];
    const float* W_be1  = (const float*)d_in[11];
    const float* b_be1  = (const float*)d_in[12];
    const float* W_be2  = (const float*)d_in[13];
    const float* b_be2  = (const float*)d_in[14];
    const float* W_cr1  = (const float*)d_in[15];
    const float* b_cr1  = (const float*)d_in[16];
    const float* W_cr2  = (const float*)d_in[17];
    const float* b_cr2  = (const float*)d_in[18];

    float* out = (float*)d_out;
    float* out_x    = out;
    float* out_ct   = out_x + (long)ROWS * D;
    float* out_enh  = out_ct + ROWS * 5;
    float* out_wb   = out_enh + ROWS;
    float* out_rel  = out_wb + ROWS;
    float* out_cred = out_rel + ROWS;

    char* cur = (char*)d_ws;
    auto alloc = [&](size_t bytes) { char* p = cur; cur += (bytes + 255) & ~(size_t)255; return p; };

    bf16* WT1    = (bf16*)alloc((size_t)N1 * 1024 * 2);     // [1280][1024]
    bf16* WT2    = (bf16*)alloc((size_t)1024 * 2048 * 2);   // [1024][2048] cd1 full
    float* W2T   = (float*)alloc((size_t)5 * 512 * 4);
    float* biasA = (float*)alloc((size_t)N1 * 4);
    bf16* xb     = (bf16*)alloc((size_t)ROWS * 1024 * 2);
    bf16* ctxb   = (bf16*)alloc((size_t)ROWS * 1024 * 2);
    bf16* YB     = (bf16*)alloc((size_t)ROWS * N1 * 2);     // 40 MB
    bf16* Hbuf   = (bf16*)alloc((size_t)ROWS * 1024 * 2);   // 32 MB
    float* part  = (float*)alloc((size_t)Bb * NCH * 1024 * 4);
    float* totl  = (float*)alloc((size_t)Bb * 1024 * 4);

    // one prep kernel: all weight transposes + W2T + bias concat
    prep_all<<<833, 256, 0, stream>>>(W_cc1, W_be1, W_cr1, W_cd1, W_cc2,
                                      b_cc1, b_be1, b_cr1, WT1, WT2, W2T, biasA);

    // ctx scan, float4 lanes (emits xb bf16 + ctx bf16 + exact fp32 x passthrough)
    scan_partial4<<<dim3(NCH, Bb), 256, 0, stream>>>(x, part);
    scan_offsets2<<<32, 256, 0, stream>>>(part, totl);
    scan_ctx4<<<dim3(NCH, Bb), 256, 0, stream>>>(x, part, totl, ctxb, xb, out_x);

    // merged GEMM: col tiles 0-9 -> YB (N=1280, K=1024, relu<768, biasA);
    //              col tiles 10-17 -> Hbuf (N=1024, K=2048 split-A, b_cd1)
    gemm_merged<<<dim3((CT1 + CT2) * MT), 256, 0, stream>>>(
        xb, ctxb, WT1, WT2, biasA, b_cd1, YB, Hbuf);

    // fused epilogue (softmax, be2, cr2, LN+gelu+cd2)
    epilogue<<<ROWS / 4, 256, 0, stream>>>(
        YB, Hbuf, W2T, b_cc2, W_be2, b_be2,
        W_cr1 + (long)1024 * 512, W_cr2, b_cr2,
        g_ln, be_ln, W_cd2, b_cd2,
        out_ct, out_enh, out_wb, out_rel, out_cred);

    (void)in_sizes; (void)n_in; (void)out_size; (void)ws_size;
}